// Round 5
// baseline (380.183 us; speedup 1.0000x reference)
//
#include <hip/hip_runtime.h>

#define NN 100000
#define NE 3200000
#define CH 8192                        // edges per chunk
#define NCB ((NE + CH - 1) / CH)       // 391 chunks
#define ITER (CH / 256)                // 32
#define NBK ((NN + 63) >> 6)           // 1563 dst-buckets of 64 nodes
#define CAP 2560                       // payload capacity per sort round (5*512)
#define NWG (NE / 64)                  // 50000 wave-groups (exact)

typedef __attribute__((ext_vector_type(8))) __bf16 bf16x8;
typedef __attribute__((ext_vector_type(4))) float f32x4;

union BF8 { unsigned short u[8]; bf16x8 v; };

// Detect label storage: int32 (harness-normalized) vs raw uint8 bool.
__global__ void kdetect(const unsigned char* __restrict__ lab8, int* __restrict__ flags) {
  __shared__ int tmp[256];
  int t = threadIdx.x;
  int s = 0;
  for (int i = t; i < 25000; i += 256) s += lab8[4 * i + 1];
  tmp[t] = s;
  __syncthreads();
  for (int d = 128; d > 0; d >>= 1) { if (t < d) tmp[t] += tmp[t + d]; __syncthreads(); }
  if (t == 0) flags[0] = (tmp[0] != 0) ? 1 : 0;
}

// labN normalize; also zeroes the global bucket histogram.
__global__ void klab(const void* __restrict__ lab, const int* __restrict__ flags,
                     int* __restrict__ labN, int* __restrict__ ghist) {
  int n = blockIdx.x * 256 + threadIdx.x;
  if (n < NBK) ghist[n] = 0;
  if (n >= NN) return;
  int v;
  if (flags[0]) v = ((const unsigned char*)lab)[n];
  else          v = ((const int*)lab)[n];
  labN[n] = (v != 0) ? 1 : 0;
}

// c01 = W_edge @ att_edge
__global__ void kc01(const float* __restrict__ We, const float* __restrict__ ae,
                     float* __restrict__ c01) {
  if (threadIdx.x == 0) {
    float c0 = 0.f, c1 = 0.f;
    for (int k = 0; k < 16; k++) { c0 += We[k] * ae[k]; c1 += We[16 + k] * ae[k]; }
    c01[0] = c0; c01[1] = c1;
  }
}

// a_src = (x@Wg)@att_src ; a_dst = (x@Wg)@att_dst  (h not materialized)
__global__ void knodeA(const float* __restrict__ x, const float* __restrict__ Wg,
                       const float* __restrict__ atts, const float* __restrict__ attd,
                       float* __restrict__ a_src, float* __restrict__ a_dst) {
  int n = blockIdx.x * 256 + threadIdx.x;
  if (n >= NN) return;
  float xi[5];
#pragma unroll
  for (int i = 0; i < 5; i++) xi[i] = x[n * 5 + i];
  float asum = 0.f, dsum = 0.f;
#pragma unroll
  for (int k = 0; k < 16; k++) {
    float acc = 0.f;
#pragma unroll
    for (int i = 0; i < 5; i++) acc += xi[i] * Wg[i * 16 + k];
    asum += acc * atts[k];
    dsum += acc * attd[k];
  }
  a_src[n] = asum; a_dst[n] = dsum;
}

// Pass 1: global bucket histogram (LDS-staged) + per-wave-group valid counts
// (cntw) + per-chunk valid counts (cntc). No blkcnt matrix anymore.
__global__ __launch_bounds__(256) void khist(const int* __restrict__ src,
                                             const int* __restrict__ dst,
                                             const int* __restrict__ labN,
                                             int* __restrict__ ghist,
                                             int* __restrict__ cntw,
                                             int* __restrict__ cntc) {
  __shared__ int hist[NBK];
  __shared__ int vsum;
  int tid = threadIdx.x, b = blockIdx.x;
  for (int i = tid; i < NBK; i += 256) hist[i] = 0;
  if (tid == 0) vsum = 0;
  __syncthreads();
  int lane = tid & 63, wid = tid >> 6;
  int wsum = 0;
  for (int it = 0; it < ITER; ++it) {
    int e = b * CH + it * 256 + tid;
    int v = 0;
    if (e < NE) {
      int s = src[e], d = dst[e];
      atomicAdd(&hist[d >> 6], 1);
      v = labN[s] & labN[d];
    }
    unsigned long long m = __ballot(v != 0);
    int c = __popcll(m);
    if (lane == 0) {
      int wg = b * 128 + it * 4 + wid;
      if (wg < NWG) cntw[wg] = c;
      wsum += c;
    }
  }
  if (lane == 0) atomicAdd(&vsum, wsum);
  __syncthreads();
  for (int i = tid; i < NBK; i += 256) {
    int h = hist[i];
    if (h) atomicAdd(&ghist[i], h);
  }
  if (tid == 0) cntc[b] = vsum;
}

// generic single-block exclusive scan; also writes off[nb] = grand total
__global__ void kscan(const int* __restrict__ cnt, int* __restrict__ off, int nb) {
  __shared__ int tmp[256];
  __shared__ int carry;
  int t = threadIdx.x;
  if (t == 0) carry = 0;
  __syncthreads();
  for (int base = 0; base < nb; base += 256) {
    int i = base + t;
    int v = (i < nb) ? cnt[i] : 0;
    tmp[t] = v;
    __syncthreads();
    for (int d = 1; d < 256; d <<= 1) {
      int add = (t >= d) ? tmp[t - d] : 0;
      __syncthreads();
      tmp[t] += add;
      __syncthreads();
    }
    if (i < nb) off[i] = carry + tmp[t] - v;
    __syncthreads();
    if (t == 0) carry += tmp[255];
    __syncthreads();
  }
  if (t == 0) off[nb] = carry;
}

// Per-chunk scan of the 128 wave-group counts -> absolute offsets offw.
// Block 0 additionally copies bb into the padded global cursor array.
__global__ __launch_bounds__(256) void kscanw(const int* __restrict__ cntw,
                                              const int* __restrict__ offc,
                                              const int* __restrict__ bb,
                                              int* __restrict__ offw,
                                              int* __restrict__ gcur) {
  int b = blockIdx.x, t = threadIdx.x;
  if (b == 0) {
    for (int i = t; i < NBK; i += 256) gcur[i * 16] = bb[i];
  }
  __shared__ int a[128];
  int wg = b * 128 + t;
  int val = 0;
  if (t < 128) {
    val = (wg < NWG) ? cntw[wg] : 0;
    a[t] = val;
  }
  __syncthreads();
  for (int d = 1; d < 128; d <<= 1) {
    int x = 0;
    if (t < 128 && t >= d) x = a[t - d];
    __syncthreads();
    if (t < 128) a[t] += x;
    __syncthreads();
  }
  if (t < 128 && wg < NWG) offw[wg] = offc[b] + a[t] - val;
}

// Pass 3 (rewritten): fully parallel, grid-stride at wave granularity.
// Bin position via global atomic cursor (64B-padded); ordered compaction via
// precomputed per-wave-group offsets. No LDS cursors, no barriers, no serial
// chain — round-4 kscat was grid-limited (13% occ, VALUBusy 3.7%, 132us).
__global__ __launch_bounds__(256) void kscat(
    const int* __restrict__ src, const int* __restrict__ dst,
    const float* __restrict__ eattr, const int* __restrict__ labN,
    const float* __restrict__ a_src, const float* __restrict__ a_dst,
    const float* __restrict__ c01, const int* __restrict__ offw,
    int* __restrict__ gcur, uint2* __restrict__ bins, float* __restrict__ out,
    float2* __restrict__ eat2, int NV) {
  float c0 = c01[0], c1 = c01[1];
  int lane = threadIdx.x & 63;
  int gw = (blockIdx.x * 256 + threadIdx.x) >> 6;
  int nw = (gridDim.x * 256) >> 6;
  for (int wg = gw; wg < NWG; wg += nw) {
    int e = wg * 64 + lane;                       // NE % 64 == 0, no tail
    int s = src[e], d = dst[e];
    float2 ea = ((const float2*)eattr)[e];
    float al = a_src[s] + a_dst[d] + ea.x * c0 + ea.y * c1;
    al = (al > 0.f) ? al : 0.2f * al;
    float exv = __expf(al);
    int pos = atomicAdd(&gcur[(d >> 6) * 16], 1);
    uint2 pl;
    pl.x = ((unsigned)s << 6) | (unsigned)(d & 63);
    pl.y = __float_as_uint(exv);
    bins[pos] = pl;
    int v = labN[s] & labN[d];
    unsigned long long m = __ballot(v != 0);
    if (v) {
      int p = offw[wg] + __popcll(m & ((1ull << lane) - 1ull));
      if (p < NV) {
        out[p] = (float)s;
        out[NV + p] = (float)d;
        eat2[p] = ea;
      }
    }
  }
}

// Pass 4: one block per 64-node bucket. Counting-sort the bucket's payloads by
// local node in LDS (int atomics only), then walk each node's contiguous run
// with 16 lanes/node accumulating in REGISTERS (no f32 atomics, no shuffles;
// x[s] loads are broadcast within each 16-lane group). Fused norm+bias+relu.
__global__ __launch_bounds__(512) void kagg(
    const uint2* __restrict__ bins, const int* __restrict__ bucket_base,
    const float* __restrict__ x, const float* __restrict__ Wg,
    const float* __restrict__ bg, float* __restrict__ xh) {
  __shared__ uint2 pay[CAP];
  __shared__ int cnt[64], inc[64], cur[64];
  __shared__ float sWg[80], sbg[16];
  int k = blockIdx.x, tid = threadIdx.x;
  if (tid < 80) sWg[tid] = Wg[tid];
  else if (tid < 96) sbg[tid - 80] = bg[tid - 80];
  int start = bucket_base[k], end = bucket_base[k + 1];
  int node0 = k << 6;
  int c = tid & 15, g = tid >> 4;     // g: 0..31
  __syncthreads();
  float w0 = sWg[c], w1 = sWg[16 + c], w2 = sWg[32 + c], w3 = sWg[48 + c], w4 = sWg[64 + c];
  float acc[2] = {0.f, 0.f}, den[2] = {0.f, 0.f};
  for (int cb = start; cb < end; cb += CAP) {        // single round in practice
    int n = min(end - cb, CAP);
    if (tid < 64) cnt[tid] = 0;
    __syncthreads();
    uint2 st0, st1, st2, st3, st4;                   // register-staged payloads
    {
      int i;
      i = tid;          if (i < n) { st0 = bins[cb + i]; atomicAdd(&cnt[st0.x & 63], 1); }
      i = tid + 512;    if (i < n) { st1 = bins[cb + i]; atomicAdd(&cnt[st1.x & 63], 1); }
      i = tid + 1024;   if (i < n) { st2 = bins[cb + i]; atomicAdd(&cnt[st2.x & 63], 1); }
      i = tid + 1536;   if (i < n) { st3 = bins[cb + i]; atomicAdd(&cnt[st3.x & 63], 1); }
      i = tid + 2048;   if (i < n) { st4 = bins[cb + i]; atomicAdd(&cnt[st4.x & 63], 1); }
    }
    __syncthreads();
    if (tid < 64) inc[tid] = cnt[tid];
    __syncthreads();
    for (int d = 1; d < 64; d <<= 1) {
      int v = 0;
      if (tid >= d && tid < 64) v = inc[tid - d];
      __syncthreads();
      if (tid < 64) inc[tid] += v;
      __syncthreads();
    }
    if (tid < 64) cur[tid] = inc[tid] - cnt[tid];
    __syncthreads();
    {
      int i;
      i = tid;          if (i < n) pay[atomicAdd(&cur[st0.x & 63], 1)] = st0;
      i = tid + 512;    if (i < n) pay[atomicAdd(&cur[st1.x & 63], 1)] = st1;
      i = tid + 1024;   if (i < n) pay[atomicAdd(&cur[st2.x & 63], 1)] = st2;
      i = tid + 1536;   if (i < n) pay[atomicAdd(&cur[st3.x & 63], 1)] = st3;
      i = tid + 2048;   if (i < n) pay[atomicAdd(&cur[st4.x & 63], 1)] = st4;
    }
    __syncthreads();
#pragma unroll
    for (int p = 0; p < 2; ++p) {
      int nd = p * 32 + g;
      int re = inc[nd], rs = re - cnt[nd];
      float a = 0.f, ds = 0.f;
      for (int idx = rs; idx < re; ++idx) {
        uint2 pl = pay[idx];                         // broadcast ds_read_b64
        int s = (int)(pl.x >> 6);
        float exv = __uint_as_float(pl.y);
        const float* xp = x + s * 5;                 // broadcast within group
        float h = xp[0] * w0 + xp[1] * w1 + xp[2] * w2 + xp[3] * w3 + xp[4] * w4;
        a += h * exv;
        ds += exv;
      }
      acc[p] += a; den[p] += ds;
    }
    __syncthreads();
  }
#pragma unroll
  for (int p = 0; p < 2; ++p) {
    int node = node0 + p * 32 + g;
    if (node < NN) {
      float dn = fmaxf(den[p], 1e-30f);
      float v = acc[p] / dn + sbg[c];
      xh[node * 16 + c] = (v > 0.f) ? v : 0.f;
    }
  }
}

// edge MLP via MFMA (round-4, unchanged). Hidden GEMM [NV,32]x[32,64] with
// trunc hi/lo bf16 split (AhBh+AhBl+AlBh); A-fragments gather directly from
// xh; W1 B-fragments live in VGPRs; fp32 epilogue + shfl reduce.
__global__ __launch_bounds__(256) void kmlp(
    const float2* __restrict__ eat2, const float* __restrict__ xh,
    const float* __restrict__ W1, const float* __restrict__ b1,
    const float* __restrict__ W2, const float* __restrict__ b2,
    float* __restrict__ out, int NV) {
  int tid = threadIdx.x;
  int lane = tid & 63, wid = tid >> 6;
  int lo4 = lane & 15, q = lane >> 4;

  BF8 bh[4], bl[4];
#pragma unroll
  for (int ct = 0; ct < 4; ct++) {
    int col = ct * 16 + lo4;
#pragma unroll
    for (int i = 0; i < 8; i++) {
      int k = q * 8 + i;
      int r = (k < 16) ? k : (k + 2);
      float w = W1[r * 64 + col];
      unsigned u = __float_as_uint(w);
      float rem = w - __uint_as_float(u & 0xffff0000u);
      bh[ct].u[i] = (unsigned short)(u >> 16);
      bl[ct].u[i] = (unsigned short)(__float_as_uint(rem) >> 16);
    }
  }
  float b1v[4], w16v[4], w17v[4], w2a[4], w2b[4];
#pragma unroll
  for (int ct = 0; ct < 4; ct++) {
    int j = ct * 16 + lo4;
    b1v[ct] = b1[j];
    w16v[ct] = W1[16 * 64 + j];
    w17v[ct] = W1[17 * 64 + j];
    w2a[ct] = W2[j * 2 + 0];
    w2b[ct] = W2[j * 2 + 1];
  }
  float bias20 = b2[0], bias21 = b2[1];

  int nwaves = gridDim.x * 4;
  int ntiles = (NV + 15) >> 4;
  for (int tb = blockIdx.x * 4 + wid; tb < ntiles; tb += nwaves) {
    int base = tb * 16;
    BF8 ah, al;
    {
      int p = base + lo4;
      float vals[8] = {0.f, 0.f, 0.f, 0.f, 0.f, 0.f, 0.f, 0.f};
      if (p < NV) {
        int node = (int)out[((q < 2) ? 0 : NV) + p];
        const float4* xp = (const float4*)(xh + node * 16 + (q & 1) * 8);
        float4 f0 = xp[0], f1 = xp[1];
        vals[0] = f0.x; vals[1] = f0.y; vals[2] = f0.z; vals[3] = f0.w;
        vals[4] = f1.x; vals[5] = f1.y; vals[6] = f1.z; vals[7] = f1.w;
      }
#pragma unroll
      for (int i = 0; i < 8; i++) {
        unsigned u = __float_as_uint(vals[i]);
        float rem = vals[i] - __uint_as_float(u & 0xffff0000u);
        ah.u[i] = (unsigned short)(u >> 16);
        al.u[i] = (unsigned short)(__float_as_uint(rem) >> 16);
      }
    }
    f32x4 acc[4];
#pragma unroll
    for (int ct = 0; ct < 4; ct++) {
      f32x4 z = {0.f, 0.f, 0.f, 0.f};
      z = __builtin_amdgcn_mfma_f32_16x16x32_bf16(ah.v, bh[ct].v, z, 0, 0, 0);
      z = __builtin_amdgcn_mfma_f32_16x16x32_bf16(ah.v, bl[ct].v, z, 0, 0, 0);
      z = __builtin_amdgcn_mfma_f32_16x16x32_bf16(al.v, bh[ct].v, z, 0, 0, 0);
      acc[ct] = z;
    }
    float o0[4], o1[4];
#pragma unroll
    for (int reg = 0; reg < 4; reg++) {
      int pr = base + q * 4 + reg;
      float2 ea = make_float2(0.f, 0.f);
      if (pr < NV) ea = eat2[pr];
      float s0 = 0.f, s1 = 0.f;
#pragma unroll
      for (int ct = 0; ct < 4; ct++) {
        float h = acc[ct][reg] + b1v[ct] + ea.x * w16v[ct] + ea.y * w17v[ct];
        h = fmaxf(h, 0.f);
        s0 += h * w2a[ct];
        s1 += h * w2b[ct];
      }
      o0[reg] = s0; o1[reg] = s1;
    }
#pragma unroll
    for (int m = 1; m < 16; m <<= 1) {
#pragma unroll
      for (int reg = 0; reg < 4; reg++) {
        o0[reg] += __shfl_xor(o0[reg], m, 64);
        o1[reg] += __shfl_xor(o1[reg], m, 64);
      }
    }
    if (lo4 == 0) {
#pragma unroll
      for (int reg = 0; reg < 4; reg++) {
        int pr = base + q * 4 + reg;
        if (pr < NV) {
          float v0 = bias20 + o0[reg], v1 = bias21 + o1[reg];
          ((float2*)(out + 2 * (size_t)NV))[pr] = make_float2(
              1.f / (1.f + __expf(-v0)), 1.f / (1.f + __expf(-v1)));
        }
      }
    }
  }
}

static inline size_t al64(size_t v) { return (v + 63) & ~(size_t)63; }

extern "C" void kernel_launch(void* const* d_in, const int* in_sizes, int n_in,
                              void* d_out, int out_size, void* d_ws, size_t ws_size,
                              hipStream_t stream) {
  const float* x     = (const float*)d_in[0];
  const int*   edges = (const int*)d_in[1];
  const float* eattr = (const float*)d_in[2];
  const void*  labels= d_in[3];
  const float* Wg    = (const float*)d_in[4];
  const float* atts  = (const float*)d_in[5];
  const float* attd  = (const float*)d_in[6];
  const float* We    = (const float*)d_in[7];
  const float* atte  = (const float*)d_in[8];
  const float* bg    = (const float*)d_in[9];
  const float* W1    = (const float*)d_in[10];
  const float* b1    = (const float*)d_in[11];
  const float* W2    = (const float*)d_in[12];
  const float* b2    = (const float*)d_in[13];
  float* out = (float*)d_out;
  const int NV = out_size / 4;
  const int* src = edges;
  const int* dst = edges + NE;

  char* w = (char*)d_ws;
  float* xh    = (float*)w;   w += al64((size_t)NN * 64);
  uint2* bins  = (uint2*)w;   w += al64((size_t)NE * 8);
  float2* eat2 = (float2*)w;  w += al64((size_t)NV * 8);
  float* a_src = (float*)w;   w += al64((size_t)NN * 4);
  float* a_dst = (float*)w;   w += al64((size_t)NN * 4);
  int* labN    = (int*)w;     w += al64((size_t)NN * 4);
  int* ghist   = (int*)w;     w += al64((size_t)NBK * 4);
  int* bb      = (int*)w;     w += al64((size_t)(NBK + 1) * 4);
  int* cntc    = (int*)w;     w += al64((size_t)NCB * 4);
  int* offc    = (int*)w;     w += al64((size_t)(NCB + 1) * 4);
  int* cntw    = (int*)w;     w += al64((size_t)NWG * 4);
  int* offw    = (int*)w;     w += al64((size_t)NWG * 4);
  int* gcur    = (int*)w;     w += al64((size_t)NBK * 16 * 4);
  float* c01   = (float*)w;   w += 64;
  int* flags   = (int*)w;     w += 64;

  kdetect<<<1, 256, 0, stream>>>((const unsigned char*)labels, flags);
  klab<<<(NN + 255) / 256, 256, 0, stream>>>(labels, flags, labN, ghist);
  kc01<<<1, 64, 0, stream>>>(We, atte, c01);
  knodeA<<<(NN + 255) / 256, 256, 0, stream>>>(x, Wg, atts, attd, a_src, a_dst);
  khist<<<NCB, 256, 0, stream>>>(src, dst, labN, ghist, cntw, cntc);
  kscan<<<1, 256, 0, stream>>>(ghist, bb, NBK);
  kscan<<<1, 256, 0, stream>>>(cntc, offc, NCB);
  kscanw<<<NCB, 256, 0, stream>>>(cntw, offc, bb, offw, gcur);
  kscat<<<2048, 256, 0, stream>>>(src, dst, eattr, labN, a_src, a_dst, c01, offw,
                                  gcur, bins, out, eat2, NV);
  kagg<<<NBK, 512, 0, stream>>>(bins, bb, x, Wg, bg, xh);
  if (NV > 0)
    kmlp<<<2048, 256, 0, stream>>>(eat2, xh, W1, b1, W2, b2, out, NV);
}

// Round 6
// 297.878 us; speedup vs baseline: 1.2763x; 1.2763x over previous
//
#include <hip/hip_runtime.h>

#define NN 100000
#define NE 3200000
#define CH 8192                        // edges per chunk
#define NCB ((NE + CH - 1) / CH)       // 391 chunks
#define ITER (CH / 256)                // 32 (khist, 256 thr)
#define ITS (CH / 512)                 // 16 (kscat, 512 thr)
#define NBK ((NN + 63) >> 6)           // 1563 dst-buckets of 64 nodes
#define CAP 2560                       // payload capacity per sort round (5*512)
#define NWG (NE / 64)                  // 50000 wave-groups (exact)

typedef __attribute__((ext_vector_type(8))) __bf16 bf16x8;
typedef __attribute__((ext_vector_type(4))) float f32x4;

union BF8 { unsigned short u[8]; bf16x8 v; };

// Detect label storage: int32 (harness-normalized) vs raw uint8 bool.
__global__ void kdetect(const unsigned char* __restrict__ lab8, int* __restrict__ flags) {
  __shared__ int tmp[256];
  int t = threadIdx.x;
  int s = 0;
  for (int i = t; i < 25000; i += 256) s += lab8[4 * i + 1];
  tmp[t] = s;
  __syncthreads();
  for (int d = 128; d > 0; d >>= 1) { if (t < d) tmp[t] += tmp[t + d]; __syncthreads(); }
  if (t == 0) flags[0] = (tmp[0] != 0) ? 1 : 0;
}

__global__ void klab(const void* __restrict__ lab, const int* __restrict__ flags,
                     int* __restrict__ labN) {
  int n = blockIdx.x * 256 + threadIdx.x;
  if (n >= NN) return;
  int v;
  if (flags[0]) v = ((const unsigned char*)lab)[n];
  else          v = ((const int*)lab)[n];
  labN[n] = (v != 0) ? 1 : 0;
}

// c01 = W_edge @ att_edge
__global__ void kc01(const float* __restrict__ We, const float* __restrict__ ae,
                     float* __restrict__ c01) {
  if (threadIdx.x == 0) {
    float c0 = 0.f, c1 = 0.f;
    for (int k = 0; k < 16; k++) { c0 += We[k] * ae[k]; c1 += We[16 + k] * ae[k]; }
    c01[0] = c0; c01[1] = c1;
  }
}

// a_src = (x@Wg)@att_src ; a_dst = (x@Wg)@att_dst  (h not materialized)
__global__ void knodeA(const float* __restrict__ x, const float* __restrict__ Wg,
                       const float* __restrict__ atts, const float* __restrict__ attd,
                       float* __restrict__ a_src, float* __restrict__ a_dst) {
  int n = blockIdx.x * 256 + threadIdx.x;
  if (n >= NN) return;
  float xi[5];
#pragma unroll
  for (int i = 0; i < 5; i++) xi[i] = x[n * 5 + i];
  float asum = 0.f, dsum = 0.f;
#pragma unroll
  for (int k = 0; k < 16; k++) {
    float acc = 0.f;
#pragma unroll
    for (int i = 0; i < 5; i++) acc += xi[i] * Wg[i * 16 + k];
    asum += acc * atts[k];
    dsum += acc * attd[k];
  }
  a_src[n] = asum; a_dst[n] = dsum;
}

// Pass 1: per-chunk bucket histogram (-> blkcnt matrix) + per-wave-group valid
// counts (cntw) + per-chunk valid counts (cntc).
__global__ __launch_bounds__(256) void khist(const int* __restrict__ src,
                                             const int* __restrict__ dst,
                                             const int* __restrict__ labN,
                                             int* __restrict__ blkcnt,
                                             int* __restrict__ cntw,
                                             int* __restrict__ cntc) {
  __shared__ int hist[NBK];
  __shared__ int vsum;
  int tid = threadIdx.x, b = blockIdx.x;
  for (int i = tid; i < NBK; i += 256) hist[i] = 0;
  if (tid == 0) vsum = 0;
  __syncthreads();
  int lane = tid & 63, wid = tid >> 6;
  int wsum = 0;
  for (int it = 0; it < ITER; ++it) {
    int e = b * CH + it * 256 + tid;
    int v = 0;
    if (e < NE) {
      int s = src[e], d = dst[e];
      atomicAdd(&hist[d >> 6], 1);
      v = labN[s] & labN[d];
    }
    unsigned long long m = __ballot(v != 0);
    int c = __popcll(m);
    if (lane == 0) {
      int wg = b * 128 + it * 4 + wid;
      if (wg < NWG) cntw[wg] = c;
      wsum += c;
    }
  }
  if (lane == 0) atomicAdd(&vsum, wsum);
  __syncthreads();
  for (int i = tid; i < NBK; i += 256) blkcnt[i * NCB + b] = hist[i];
  if (tid == 0) cntc[b] = vsum;
}

// Pass 2a: per-bucket exclusive scan over chunks (row of blkcnt), totals out.
__global__ __launch_bounds__(256) void kscanb(int* __restrict__ blkcnt,
                                              int* __restrict__ total) {
  __shared__ int a[512];
  int row = blockIdx.x, t = threadIdx.x;
  int* p = blkcnt + row * NCB;
  int o0 = (t < NCB) ? p[t] : 0;
  int o1 = (t + 256 < NCB) ? p[t + 256] : 0;
  a[t] = o0; a[t + 256] = o1;
  __syncthreads();
  for (int d = 1; d < 512; d <<= 1) {
    int x0 = (t >= d) ? a[t - d] : 0;
    int x1 = (t + 256 >= d) ? a[t + 256 - d] : 0;
    __syncthreads();
    a[t] += x0; a[t + 256] += x1;
    __syncthreads();
  }
  if (t < NCB) p[t] = a[t] - o0;
  if (t + 256 < NCB) p[t + 256] = a[t + 256] - o1;
  if (t == 0) total[row] = a[NCB - 1];
}

// generic single-block exclusive scan; also writes off[nb] = grand total
__global__ void kscan(const int* __restrict__ cnt, int* __restrict__ off, int nb) {
  __shared__ int tmp[256];
  __shared__ int carry;
  int t = threadIdx.x;
  if (t == 0) carry = 0;
  __syncthreads();
  for (int base = 0; base < nb; base += 256) {
    int i = base + t;
    int v = (i < nb) ? cnt[i] : 0;
    tmp[t] = v;
    __syncthreads();
    for (int d = 1; d < 256; d <<= 1) {
      int add = (t >= d) ? tmp[t - d] : 0;
      __syncthreads();
      tmp[t] += add;
      __syncthreads();
    }
    if (i < nb) off[i] = carry + tmp[t] - v;
    __syncthreads();
    if (t == 0) carry += tmp[255];
    __syncthreads();
  }
  if (t == 0) off[nb] = carry;
}

// Per-chunk scan of the 128 wave-group counts -> absolute offsets offw.
__global__ __launch_bounds__(128) void kscanw(const int* __restrict__ cntw,
                                              const int* __restrict__ offc,
                                              int* __restrict__ offw) {
  int b = blockIdx.x, t = threadIdx.x;
  __shared__ int a[128];
  int wg = b * 128 + t;
  int val = (wg < NWG) ? cntw[wg] : 0;
  a[t] = val;
  __syncthreads();
  for (int d = 1; d < 128; d <<= 1) {
    int x = (t >= d) ? a[t - d] : 0;
    __syncthreads();
    a[t] += x;
    __syncthreads();
  }
  if (wg < NWG) offw[wg] = offc[b] + a[t] - val;
}

// Pass 3: barrier-free scatter. Deterministic per-chunk bucket bases (round-4,
// chunk-clustered bin writes, WRITE back to ~124MB) + per-wave-group offw
// compaction (round-5, no lbase chain). One barrier after cursor init; then
// 8 waves x 16 independent iterations free-run for latency hiding. No global
// atomics (round-5's 225MB write-amp + atomic-return stalls are gone).
__global__ __launch_bounds__(512) void kscat(
    const int* __restrict__ src, const int* __restrict__ dst,
    const float* __restrict__ eattr, const int* __restrict__ labN,
    const float* __restrict__ a_src, const float* __restrict__ a_dst,
    const float* __restrict__ c01, const int* __restrict__ bucket_base,
    const int* __restrict__ blkcnt, const int* __restrict__ offw,
    uint2* __restrict__ bins, float* __restrict__ out,
    float2* __restrict__ eat2, int NV) {
  __shared__ int cur[NBK];
  int b = blockIdx.x, tid = threadIdx.x;
  for (int i = tid; i < NBK; i += 512) cur[i] = bucket_base[i] + blkcnt[i * NCB + b];
  float c0 = c01[0], c1 = c01[1];
  __syncthreads();
  int lane = tid & 63, wid = tid >> 6;
  for (int it = 0; it < ITS; ++it) {
    int e = b * CH + it * 512 + tid;
    if (e >= NE) break;                       // NE%64==0: wave-uniform exit
    int s = src[e], d = dst[e];
    float2 ea = ((const float2*)eattr)[e];
    float al = a_src[s] + a_dst[d] + ea.x * c0 + ea.y * c1;
    al = (al > 0.f) ? al : 0.2f * al;
    float exv = __expf(al);
    int pos = atomicAdd(&cur[d >> 6], 1);
    uint2 pl;
    pl.x = ((unsigned)s << 6) | (unsigned)(d & 63);
    pl.y = __float_as_uint(exv);
    bins[pos] = pl;
    int v = labN[s] & labN[d];
    unsigned long long m = __ballot(v != 0);
    if (v) {
      int wg = b * 128 + it * 8 + wid;        // == e/64, matches khist's cntw
      int p = offw[wg] + __popcll(m & ((1ull << lane) - 1ull));
      if (p < NV) {
        out[p] = (float)s;
        out[NV + p] = (float)d;
        eat2[p] = ea;
      }
    }
  }
}

// Pass 4: one block per 64-node bucket. Counting-sort the bucket's payloads by
// local node in LDS (int atomics only), then walk each node's contiguous run
// with 16 lanes/node accumulating in REGISTERS (no f32 atomics, no shuffles;
// x[s] loads are broadcast within each 16-lane group). Fused norm+bias+relu.
__global__ __launch_bounds__(512) void kagg(
    const uint2* __restrict__ bins, const int* __restrict__ bucket_base,
    const float* __restrict__ x, const float* __restrict__ Wg,
    const float* __restrict__ bg, float* __restrict__ xh) {
  __shared__ uint2 pay[CAP];
  __shared__ int cnt[64], inc[64], cur[64];
  __shared__ float sWg[80], sbg[16];
  int k = blockIdx.x, tid = threadIdx.x;
  if (tid < 80) sWg[tid] = Wg[tid];
  else if (tid < 96) sbg[tid - 80] = bg[tid - 80];
  int start = bucket_base[k], end = bucket_base[k + 1];
  int node0 = k << 6;
  int c = tid & 15, g = tid >> 4;     // g: 0..31
  __syncthreads();
  float w0 = sWg[c], w1 = sWg[16 + c], w2 = sWg[32 + c], w3 = sWg[48 + c], w4 = sWg[64 + c];
  float acc[2] = {0.f, 0.f}, den[2] = {0.f, 0.f};
  for (int cb = start; cb < end; cb += CAP) {        // single round in practice
    int n = min(end - cb, CAP);
    if (tid < 64) cnt[tid] = 0;
    __syncthreads();
    uint2 st0, st1, st2, st3, st4;                   // register-staged payloads
    {
      int i;
      i = tid;          if (i < n) { st0 = bins[cb + i]; atomicAdd(&cnt[st0.x & 63], 1); }
      i = tid + 512;    if (i < n) { st1 = bins[cb + i]; atomicAdd(&cnt[st1.x & 63], 1); }
      i = tid + 1024;   if (i < n) { st2 = bins[cb + i]; atomicAdd(&cnt[st2.x & 63], 1); }
      i = tid + 1536;   if (i < n) { st3 = bins[cb + i]; atomicAdd(&cnt[st3.x & 63], 1); }
      i = tid + 2048;   if (i < n) { st4 = bins[cb + i]; atomicAdd(&cnt[st4.x & 63], 1); }
    }
    __syncthreads();
    if (tid < 64) inc[tid] = cnt[tid];
    __syncthreads();
    for (int d = 1; d < 64; d <<= 1) {
      int v = 0;
      if (tid >= d && tid < 64) v = inc[tid - d];
      __syncthreads();
      if (tid < 64) inc[tid] += v;
      __syncthreads();
    }
    if (tid < 64) cur[tid] = inc[tid] - cnt[tid];
    __syncthreads();
    {
      int i;
      i = tid;          if (i < n) pay[atomicAdd(&cur[st0.x & 63], 1)] = st0;
      i = tid + 512;    if (i < n) pay[atomicAdd(&cur[st1.x & 63], 1)] = st1;
      i = tid + 1024;   if (i < n) pay[atomicAdd(&cur[st2.x & 63], 1)] = st2;
      i = tid + 1536;   if (i < n) pay[atomicAdd(&cur[st3.x & 63], 1)] = st3;
      i = tid + 2048;   if (i < n) pay[atomicAdd(&cur[st4.x & 63], 1)] = st4;
    }
    __syncthreads();
#pragma unroll
    for (int p = 0; p < 2; ++p) {
      int nd = p * 32 + g;
      int re = inc[nd], rs = re - cnt[nd];
      float a = 0.f, ds = 0.f;
      for (int idx = rs; idx < re; ++idx) {
        uint2 pl = pay[idx];                         // broadcast ds_read_b64
        int s = (int)(pl.x >> 6);
        float exv = __uint_as_float(pl.y);
        const float* xp = x + s * 5;                 // broadcast within group
        float h = xp[0] * w0 + xp[1] * w1 + xp[2] * w2 + xp[3] * w3 + xp[4] * w4;
        a += h * exv;
        ds += exv;
      }
      acc[p] += a; den[p] += ds;
    }
    __syncthreads();
  }
#pragma unroll
  for (int p = 0; p < 2; ++p) {
    int node = node0 + p * 32 + g;
    if (node < NN) {
      float dn = fmaxf(den[p], 1e-30f);
      float v = acc[p] / dn + sbg[c];
      xh[node * 16 + c] = (v > 0.f) ? v : 0.f;
    }
  }
}

// edge MLP via MFMA (round-4, unchanged). Hidden GEMM [NV,32]x[32,64] with
// trunc hi/lo bf16 split (AhBh+AhBl+AlBh); A-fragments gather directly from
// xh; W1 B-fragments live in VGPRs; fp32 epilogue + shfl reduce.
__global__ __launch_bounds__(256) void kmlp(
    const float2* __restrict__ eat2, const float* __restrict__ xh,
    const float* __restrict__ W1, const float* __restrict__ b1,
    const float* __restrict__ W2, const float* __restrict__ b2,
    float* __restrict__ out, int NV) {
  int tid = threadIdx.x;
  int lane = tid & 63, wid = tid >> 6;
  int lo4 = lane & 15, q = lane >> 4;

  BF8 bh[4], bl[4];
#pragma unroll
  for (int ct = 0; ct < 4; ct++) {
    int col = ct * 16 + lo4;
#pragma unroll
    for (int i = 0; i < 8; i++) {
      int k = q * 8 + i;
      int r = (k < 16) ? k : (k + 2);
      float w = W1[r * 64 + col];
      unsigned u = __float_as_uint(w);
      float rem = w - __uint_as_float(u & 0xffff0000u);
      bh[ct].u[i] = (unsigned short)(u >> 16);
      bl[ct].u[i] = (unsigned short)(__float_as_uint(rem) >> 16);
    }
  }
  float b1v[4], w16v[4], w17v[4], w2a[4], w2b[4];
#pragma unroll
  for (int ct = 0; ct < 4; ct++) {
    int j = ct * 16 + lo4;
    b1v[ct] = b1[j];
    w16v[ct] = W1[16 * 64 + j];
    w17v[ct] = W1[17 * 64 + j];
    w2a[ct] = W2[j * 2 + 0];
    w2b[ct] = W2[j * 2 + 1];
  }
  float bias20 = b2[0], bias21 = b2[1];

  int nwaves = gridDim.x * 4;
  int ntiles = (NV + 15) >> 4;
  for (int tb = blockIdx.x * 4 + wid; tb < ntiles; tb += nwaves) {
    int base = tb * 16;
    BF8 ah, al;
    {
      int p = base + lo4;
      float vals[8] = {0.f, 0.f, 0.f, 0.f, 0.f, 0.f, 0.f, 0.f};
      if (p < NV) {
        int node = (int)out[((q < 2) ? 0 : NV) + p];
        const float4* xp = (const float4*)(xh + node * 16 + (q & 1) * 8);
        float4 f0 = xp[0], f1 = xp[1];
        vals[0] = f0.x; vals[1] = f0.y; vals[2] = f0.z; vals[3] = f0.w;
        vals[4] = f1.x; vals[5] = f1.y; vals[6] = f1.z; vals[7] = f1.w;
      }
#pragma unroll
      for (int i = 0; i < 8; i++) {
        unsigned u = __float_as_uint(vals[i]);
        float rem = vals[i] - __uint_as_float(u & 0xffff0000u);
        ah.u[i] = (unsigned short)(u >> 16);
        al.u[i] = (unsigned short)(__float_as_uint(rem) >> 16);
      }
    }
    f32x4 acc[4];
#pragma unroll
    for (int ct = 0; ct < 4; ct++) {
      f32x4 z = {0.f, 0.f, 0.f, 0.f};
      z = __builtin_amdgcn_mfma_f32_16x16x32_bf16(ah.v, bh[ct].v, z, 0, 0, 0);
      z = __builtin_amdgcn_mfma_f32_16x16x32_bf16(ah.v, bl[ct].v, z, 0, 0, 0);
      z = __builtin_amdgcn_mfma_f32_16x16x32_bf16(al.v, bh[ct].v, z, 0, 0, 0);
      acc[ct] = z;
    }
    float o0[4], o1[4];
#pragma unroll
    for (int reg = 0; reg < 4; reg++) {
      int pr = base + q * 4 + reg;
      float2 ea = make_float2(0.f, 0.f);
      if (pr < NV) ea = eat2[pr];
      float s0 = 0.f, s1 = 0.f;
#pragma unroll
      for (int ct = 0; ct < 4; ct++) {
        float h = acc[ct][reg] + b1v[ct] + ea.x * w16v[ct] + ea.y * w17v[ct];
        h = fmaxf(h, 0.f);
        s0 += h * w2a[ct];
        s1 += h * w2b[ct];
      }
      o0[reg] = s0; o1[reg] = s1;
    }
#pragma unroll
    for (int m = 1; m < 16; m <<= 1) {
#pragma unroll
      for (int reg = 0; reg < 4; reg++) {
        o0[reg] += __shfl_xor(o0[reg], m, 64);
        o1[reg] += __shfl_xor(o1[reg], m, 64);
      }
    }
    if (lo4 == 0) {
#pragma unroll
      for (int reg = 0; reg < 4; reg++) {
        int pr = base + q * 4 + reg;
        if (pr < NV) {
          float v0 = bias20 + o0[reg], v1 = bias21 + o1[reg];
          ((float2*)(out + 2 * (size_t)NV))[pr] = make_float2(
              1.f / (1.f + __expf(-v0)), 1.f / (1.f + __expf(-v1)));
        }
      }
    }
  }
}

static inline size_t al64(size_t v) { return (v + 63) & ~(size_t)63; }

extern "C" void kernel_launch(void* const* d_in, const int* in_sizes, int n_in,
                              void* d_out, int out_size, void* d_ws, size_t ws_size,
                              hipStream_t stream) {
  const float* x     = (const float*)d_in[0];
  const int*   edges = (const int*)d_in[1];
  const float* eattr = (const float*)d_in[2];
  const void*  labels= d_in[3];
  const float* Wg    = (const float*)d_in[4];
  const float* atts  = (const float*)d_in[5];
  const float* attd  = (const float*)d_in[6];
  const float* We    = (const float*)d_in[7];
  const float* atte  = (const float*)d_in[8];
  const float* bg    = (const float*)d_in[9];
  const float* W1    = (const float*)d_in[10];
  const float* b1    = (const float*)d_in[11];
  const float* W2    = (const float*)d_in[12];
  const float* b2    = (const float*)d_in[13];
  float* out = (float*)d_out;
  const int NV = out_size / 4;
  const int* src = edges;
  const int* dst = edges + NE;

  char* w = (char*)d_ws;
  float* xh    = (float*)w;   w += al64((size_t)NN * 64);
  uint2* bins  = (uint2*)w;   w += al64((size_t)NE * 8);
  float2* eat2 = (float2*)w;  w += al64((size_t)NV * 8);
  float* a_src = (float*)w;   w += al64((size_t)NN * 4);
  float* a_dst = (float*)w;   w += al64((size_t)NN * 4);
  int* labN    = (int*)w;     w += al64((size_t)NN * 4);
  int* blkcnt  = (int*)w;     w += al64((size_t)NBK * NCB * 4);
  int* total   = (int*)w;     w += al64((size_t)NBK * 4);
  int* bb      = (int*)w;     w += al64((size_t)(NBK + 1) * 4);
  int* cntc    = (int*)w;     w += al64((size_t)NCB * 4);
  int* offc    = (int*)w;     w += al64((size_t)(NCB + 1) * 4);
  int* cntw    = (int*)w;     w += al64((size_t)NWG * 4);
  int* offw    = (int*)w;     w += al64((size_t)NWG * 4);
  float* c01   = (float*)w;   w += 64;
  int* flags   = (int*)w;     w += 64;

  kdetect<<<1, 256, 0, stream>>>((const unsigned char*)labels, flags);
  klab<<<(NN + 255) / 256, 256, 0, stream>>>(labels, flags, labN);
  kc01<<<1, 64, 0, stream>>>(We, atte, c01);
  knodeA<<<(NN + 255) / 256, 256, 0, stream>>>(x, Wg, atts, attd, a_src, a_dst);
  khist<<<NCB, 256, 0, stream>>>(src, dst, labN, blkcnt, cntw, cntc);
  kscanb<<<NBK, 256, 0, stream>>>(blkcnt, total);
  kscan<<<1, 256, 0, stream>>>(total, bb, NBK);
  kscan<<<1, 256, 0, stream>>>(cntc, offc, NCB);
  kscanw<<<NCB, 128, 0, stream>>>(cntw, offc, offw);
  kscat<<<NCB, 512, 0, stream>>>(src, dst, eattr, labN, a_src, a_dst, c01, bb,
                                 blkcnt, offw, bins, out, eat2, NV);
  kagg<<<NBK, 512, 0, stream>>>(bins, bb, x, Wg, bg, xh);
  if (NV > 0)
    kmlp<<<2048, 256, 0, stream>>>(eat2, xh, W1, b1, W2, b2, out, NV);
}

// Round 7
// 294.249 us; speedup vs baseline: 1.2920x; 1.0123x over previous
//
#include <hip/hip_runtime.h>

#define NN 100000
#define NE 3200000
#define CH 2048                        // edges per chunk
#define NCB ((NE + CH - 1) / CH)       // 1563 chunks
#define ITER (CH / 256)                // 8 iterations (khist/kscat, 256 thr)
#define NBK ((NN + 63) >> 6)           // 1563 dst-buckets of 64 nodes
#define CAP 2560                       // payload capacity per sort round (5*512)
#define NWG (NE / 64)                  // 50000 wave-groups (exact)
#define NSTRIP 8
#define SLEN ((NCB + NSTRIP - 1) / NSTRIP)   // 196 chunks per strip

typedef __attribute__((ext_vector_type(8))) __bf16 bf16x8;
typedef __attribute__((ext_vector_type(4))) float f32x4;

union BF8 { unsigned short u[8]; bf16x8 v; };

// Detect label storage: int32 (harness-normalized) vs raw uint8 bool.
__global__ void kdetect(const unsigned char* __restrict__ lab8, int* __restrict__ flags) {
  __shared__ int tmp[256];
  int t = threadIdx.x;
  int s = 0;
  for (int i = t; i < 25000; i += 256) s += lab8[4 * i + 1];
  tmp[t] = s;
  __syncthreads();
  for (int d = 128; d > 0; d >>= 1) { if (t < d) tmp[t] += tmp[t + d]; __syncthreads(); }
  if (t == 0) flags[0] = (tmp[0] != 0) ? 1 : 0;
}

__global__ void klab(const void* __restrict__ lab, const int* __restrict__ flags,
                     int* __restrict__ labN) {
  int n = blockIdx.x * 256 + threadIdx.x;
  if (n >= NN) return;
  int v;
  if (flags[0]) v = ((const unsigned char*)lab)[n];
  else          v = ((const int*)lab)[n];
  labN[n] = (v != 0) ? 1 : 0;
}

// c01 = W_edge @ att_edge
__global__ void kc01(const float* __restrict__ We, const float* __restrict__ ae,
                     float* __restrict__ c01) {
  if (threadIdx.x == 0) {
    float c0 = 0.f, c1 = 0.f;
    for (int k = 0; k < 16; k++) { c0 += We[k] * ae[k]; c1 += We[16 + k] * ae[k]; }
    c01[0] = c0; c01[1] = c1;
  }
}

// Per-node attention partials PACKED with the label so kscat does 2x8B
// gathers instead of 4x4B: pka[n]={a_src,lab}, pkd[n]={a_dst,lab}.
__global__ void knodeA(const float* __restrict__ x, const float* __restrict__ Wg,
                       const float* __restrict__ atts, const float* __restrict__ attd,
                       const int* __restrict__ labN,
                       float2* __restrict__ pka, float2* __restrict__ pkd) {
  int n = blockIdx.x * 256 + threadIdx.x;
  if (n >= NN) return;
  float xi[5];
#pragma unroll
  for (int i = 0; i < 5; i++) xi[i] = x[n * 5 + i];
  float asum = 0.f, dsum = 0.f;
#pragma unroll
  for (int k = 0; k < 16; k++) {
    float acc = 0.f;
#pragma unroll
    for (int i = 0; i < 5; i++) acc += xi[i] * Wg[i * 16 + k];
    asum += acc * atts[k];
    dsum += acc * attd[k];
  }
  float lab = labN[n] ? 1.f : 0.f;
  pka[n] = make_float2(asum, lab);
  pkd[n] = make_float2(dsum, lab);
}

// Pass 1: per-chunk bucket histogram -> TRANSPOSED blkcnt[chunk][bucket]
// (contiguous per block), + per-wave-group valid counts + per-chunk counts.
__global__ __launch_bounds__(256) void khist(const int* __restrict__ src,
                                             const int* __restrict__ dst,
                                             const int* __restrict__ labN,
                                             int* __restrict__ blkcnt,
                                             int* __restrict__ cntw,
                                             int* __restrict__ cntc) {
  __shared__ int hist[NBK];
  __shared__ int vsum;
  int tid = threadIdx.x, b = blockIdx.x;
  for (int i = tid; i < NBK; i += 256) hist[i] = 0;
  if (tid == 0) vsum = 0;
  __syncthreads();
  int lane = tid & 63, wid = tid >> 6;
  int wsum = 0;
  for (int it = 0; it < ITER; ++it) {
    int e = b * CH + it * 256 + tid;
    int v = 0;
    if (e < NE) {
      int s = src[e], d = dst[e];
      atomicAdd(&hist[d >> 6], 1);
      v = labN[s] & labN[d];
    }
    unsigned long long m = __ballot(v != 0);
    int c = __popcll(m);
    if (lane == 0) {
      int wg = b * (CH / 64) + it * 4 + wid;
      if (wg < NWG) cntw[wg] = c;
      wsum += c;
    }
  }
  if (lane == 0) atomicAdd(&vsum, wsum);
  __syncthreads();
  int* row = blkcnt + (size_t)b * NBK;
  for (int i = tid; i < NBK; i += 256) row[i] = hist[i];
  if (tid == 0) cntc[b] = vsum;
}

// Column-scan phase 1: per (bucket, strip), serial exclusive scan over the
// strip's chunks, in place; strip total -> ssum[strip][bucket]. All accesses
// coalesced across the bucket-threads.
__global__ __launch_bounds__(256) void kscanc1(int* __restrict__ blkcnt,
                                               int* __restrict__ ssum) {
  int i = blockIdx.x * 256 + threadIdx.x;
  int st = blockIdx.y;
  if (i >= NBK) return;
  int c0 = st * SLEN, c1 = min(c0 + SLEN, NCB);
  int run = 0;
#pragma unroll 4
  for (int c = c0; c < c1; c++) {
    int* p = blkcnt + (size_t)c * NBK + i;
    int v = *p;
    *p = run;
    run += v;
  }
  ssum[st * NBK + i] = run;
}

// Column-scan phase 2: exclusive scan over the 8 strips per bucket + totals.
__global__ __launch_bounds__(256) void kscanc2(int* __restrict__ ssum,
                                               int* __restrict__ total) {
  int i = blockIdx.x * 256 + threadIdx.x;
  if (i >= NBK) return;
  int run = 0;
#pragma unroll
  for (int st = 0; st < NSTRIP; st++) {
    int v = ssum[st * NBK + i];
    ssum[st * NBK + i] = run;
    run += v;
  }
  total[i] = run;
}

// generic single-block exclusive scan; also writes off[nb] = grand total
__global__ void kscan(const int* __restrict__ cnt, int* __restrict__ off, int nb) {
  __shared__ int tmp[256];
  __shared__ int carry;
  int t = threadIdx.x;
  if (t == 0) carry = 0;
  __syncthreads();
  for (int base = 0; base < nb; base += 256) {
    int i = base + t;
    int v = (i < nb) ? cnt[i] : 0;
    tmp[t] = v;
    __syncthreads();
    for (int d = 1; d < 256; d <<= 1) {
      int add = (t >= d) ? tmp[t - d] : 0;
      __syncthreads();
      tmp[t] += add;
      __syncthreads();
    }
    if (i < nb) off[i] = carry + tmp[t] - v;
    __syncthreads();
    if (t == 0) carry += tmp[255];
    __syncthreads();
  }
  if (t == 0) off[nb] = carry;
}

// Segmented (32-wide, one segment per chunk) scan of wave-group counts.
__global__ __launch_bounds__(128) void kscanw(const int* __restrict__ cntw,
                                              const int* __restrict__ offc,
                                              int* __restrict__ offw) {
  __shared__ int a[128];
  int t = threadIdx.x;
  int wg = blockIdx.x * 128 + t;
  int l = t & 31;
  int val = (wg < NWG) ? cntw[wg] : 0;
  a[t] = val;
  __syncthreads();
  for (int d = 1; d < 32; d <<= 1) {
    int x = (l >= d) ? a[t - d] : 0;
    __syncthreads();
    a[t] += x;
    __syncthreads();
  }
  if (wg < NWG) offw[wg] = offc[wg >> 5] + a[t] - val;
}

// Pass 3: fine-grained (2048-edge chunks, 1563 blocks), barrier-free after
// cursor init. Cursor init is fully coalesced (transposed blkcnt + ssum).
// XCD-bijective chunk swizzle keeps same-XCD blocks on adjacent chunks so
// their small bucket-runs merge in one L2. 2 packed 8B gathers per edge.
__global__ __launch_bounds__(256) void kscat(
    const int* __restrict__ src, const int* __restrict__ dst,
    const float* __restrict__ eattr,
    const float2* __restrict__ pka, const float2* __restrict__ pkd,
    const float* __restrict__ c01, const int* __restrict__ bucket_base,
    const int* __restrict__ blkcnt, const int* __restrict__ ssum,
    const int* __restrict__ offw,
    uint2* __restrict__ bins, float* __restrict__ out,
    float2* __restrict__ eat2, int NV) {
  __shared__ int cur[NBK];
  int ob = blockIdx.x, tid = threadIdx.x;
  // bijective XCD swizzle (NCB % 8 != 0 safe)
  int xcd = ob & 7, loc = ob >> 3;
  const int q = NCB >> 3, r = NCB & 7;
  int b = ((xcd < r) ? xcd * (q + 1) : r * (q + 1) + (xcd - r) * q) + loc;
  const int* bc = blkcnt + (size_t)b * NBK;
  const int* ss = ssum + (size_t)(b / SLEN) * NBK;
  for (int i = tid; i < NBK; i += 256) cur[i] = bucket_base[i] + ss[i] + bc[i];
  float c0 = c01[0], c1 = c01[1];
  __syncthreads();
  int lane = tid & 63, wid = tid >> 6;
  for (int it = 0; it < ITER; ++it) {
    int e = b * CH + it * 256 + tid;
    if (e >= NE) break;                       // NE%256==0: uniform exit
    int s = src[e], d = dst[e];
    float2 ea = ((const float2*)eattr)[e];
    float2 ga = pka[s], gd = pkd[d];
    float al = ga.x + gd.x + ea.x * c0 + ea.y * c1;
    al = (al > 0.f) ? al : 0.2f * al;
    float exv = __expf(al);
    int pos = atomicAdd(&cur[d >> 6], 1);
    uint2 pl;
    pl.x = ((unsigned)s << 6) | (unsigned)(d & 63);
    pl.y = __float_as_uint(exv);
    bins[pos] = pl;
    int v = (ga.y != 0.f) && (gd.y != 0.f);
    unsigned long long m = __ballot(v);
    if (v) {
      int wg = b * (CH / 64) + it * 4 + wid;  // == e/64, matches khist cntw
      int p = offw[wg] + __popcll(m & ((1ull << lane) - 1ull));
      if (p < NV) {
        out[p] = (float)s;
        out[NV + p] = (float)d;
        eat2[p] = ea;
      }
    }
  }
}

// Pass 4: one block per 64-node bucket. Counting-sort the bucket's payloads by
// local node in LDS (int atomics only), then walk each node's contiguous run
// with 16 lanes/node accumulating in REGISTERS. Fused norm+bias+relu.
__global__ __launch_bounds__(512) void kagg(
    const uint2* __restrict__ bins, const int* __restrict__ bucket_base,
    const float* __restrict__ x, const float* __restrict__ Wg,
    const float* __restrict__ bg, float* __restrict__ xh) {
  __shared__ uint2 pay[CAP];
  __shared__ int cnt[64], inc[64], cur[64];
  __shared__ float sWg[80], sbg[16];
  int k = blockIdx.x, tid = threadIdx.x;
  if (tid < 80) sWg[tid] = Wg[tid];
  else if (tid < 96) sbg[tid - 80] = bg[tid - 80];
  int start = bucket_base[k], end = bucket_base[k + 1];
  int node0 = k << 6;
  int c = tid & 15, g = tid >> 4;     // g: 0..31
  __syncthreads();
  float w0 = sWg[c], w1 = sWg[16 + c], w2 = sWg[32 + c], w3 = sWg[48 + c], w4 = sWg[64 + c];
  float acc[2] = {0.f, 0.f}, den[2] = {0.f, 0.f};
  for (int cb = start; cb < end; cb += CAP) {        // single round in practice
    int n = min(end - cb, CAP);
    if (tid < 64) cnt[tid] = 0;
    __syncthreads();
    uint2 st0, st1, st2, st3, st4;                   // register-staged payloads
    {
      int i;
      i = tid;          if (i < n) { st0 = bins[cb + i]; atomicAdd(&cnt[st0.x & 63], 1); }
      i = tid + 512;    if (i < n) { st1 = bins[cb + i]; atomicAdd(&cnt[st1.x & 63], 1); }
      i = tid + 1024;   if (i < n) { st2 = bins[cb + i]; atomicAdd(&cnt[st2.x & 63], 1); }
      i = tid + 1536;   if (i < n) { st3 = bins[cb + i]; atomicAdd(&cnt[st3.x & 63], 1); }
      i = tid + 2048;   if (i < n) { st4 = bins[cb + i]; atomicAdd(&cnt[st4.x & 63], 1); }
    }
    __syncthreads();
    if (tid < 64) inc[tid] = cnt[tid];
    __syncthreads();
    for (int d = 1; d < 64; d <<= 1) {
      int v = 0;
      if (tid >= d && tid < 64) v = inc[tid - d];
      __syncthreads();
      if (tid < 64) inc[tid] += v;
      __syncthreads();
    }
    if (tid < 64) cur[tid] = inc[tid] - cnt[tid];
    __syncthreads();
    {
      int i;
      i = tid;          if (i < n) pay[atomicAdd(&cur[st0.x & 63], 1)] = st0;
      i = tid + 512;    if (i < n) pay[atomicAdd(&cur[st1.x & 63], 1)] = st1;
      i = tid + 1024;   if (i < n) pay[atomicAdd(&cur[st2.x & 63], 1)] = st2;
      i = tid + 1536;   if (i < n) pay[atomicAdd(&cur[st3.x & 63], 1)] = st3;
      i = tid + 2048;   if (i < n) pay[atomicAdd(&cur[st4.x & 63], 1)] = st4;
    }
    __syncthreads();
#pragma unroll
    for (int p = 0; p < 2; ++p) {
      int nd = p * 32 + g;
      int re = inc[nd], rs = re - cnt[nd];
      float a = 0.f, ds = 0.f;
      for (int idx = rs; idx < re; ++idx) {
        uint2 pl = pay[idx];                         // broadcast ds_read_b64
        int s = (int)(pl.x >> 6);
        float exv = __uint_as_float(pl.y);
        const float* xp = x + s * 5;                 // broadcast within group
        float h = xp[0] * w0 + xp[1] * w1 + xp[2] * w2 + xp[3] * w3 + xp[4] * w4;
        a += h * exv;
        ds += exv;
      }
      acc[p] += a; den[p] += ds;
    }
    __syncthreads();
  }
#pragma unroll
  for (int p = 0; p < 2; ++p) {
    int node = node0 + p * 32 + g;
    if (node < NN) {
      float dn = fmaxf(den[p], 1e-30f);
      float v = acc[p] / dn + sbg[c];
      xh[node * 16 + c] = (v > 0.f) ? v : 0.f;
    }
  }
}

// edge MLP via MFMA (unchanged). Hidden GEMM [NV,32]x[32,64] with trunc hi/lo
// bf16 split (AhBh+AhBl+AlBh); A-fragments gather directly from xh; W1
// B-fragments live in VGPRs; fp32 epilogue + shfl reduce.
__global__ __launch_bounds__(256) void kmlp(
    const float2* __restrict__ eat2, const float* __restrict__ xh,
    const float* __restrict__ W1, const float* __restrict__ b1,
    const float* __restrict__ W2, const float* __restrict__ b2,
    float* __restrict__ out, int NV) {
  int tid = threadIdx.x;
  int lane = tid & 63, wid = tid >> 6;
  int lo4 = lane & 15, q = lane >> 4;

  BF8 bh[4], bl[4];
#pragma unroll
  for (int ct = 0; ct < 4; ct++) {
    int col = ct * 16 + lo4;
#pragma unroll
    for (int i = 0; i < 8; i++) {
      int k = q * 8 + i;
      int r = (k < 16) ? k : (k + 2);
      float w = W1[r * 64 + col];
      unsigned u = __float_as_uint(w);
      float rem = w - __uint_as_float(u & 0xffff0000u);
      bh[ct].u[i] = (unsigned short)(u >> 16);
      bl[ct].u[i] = (unsigned short)(__float_as_uint(rem) >> 16);
    }
  }
  float b1v[4], w16v[4], w17v[4], w2a[4], w2b[4];
#pragma unroll
  for (int ct = 0; ct < 4; ct++) {
    int j = ct * 16 + lo4;
    b1v[ct] = b1[j];
    w16v[ct] = W1[16 * 64 + j];
    w17v[ct] = W1[17 * 64 + j];
    w2a[ct] = W2[j * 2 + 0];
    w2b[ct] = W2[j * 2 + 1];
  }
  float bias20 = b2[0], bias21 = b2[1];

  int nwaves = gridDim.x * 4;
  int ntiles = (NV + 15) >> 4;
  for (int tb = blockIdx.x * 4 + wid; tb < ntiles; tb += nwaves) {
    int base = tb * 16;
    BF8 ah, al;
    {
      int p = base + lo4;
      float vals[8] = {0.f, 0.f, 0.f, 0.f, 0.f, 0.f, 0.f, 0.f};
      if (p < NV) {
        int node = (int)out[((q < 2) ? 0 : NV) + p];
        const float4* xp = (const float4*)(xh + node * 16 + (q & 1) * 8);
        float4 f0 = xp[0], f1 = xp[1];
        vals[0] = f0.x; vals[1] = f0.y; vals[2] = f0.z; vals[3] = f0.w;
        vals[4] = f1.x; vals[5] = f1.y; vals[6] = f1.z; vals[7] = f1.w;
      }
#pragma unroll
      for (int i = 0; i < 8; i++) {
        unsigned u = __float_as_uint(vals[i]);
        float rem = vals[i] - __uint_as_float(u & 0xffff0000u);
        ah.u[i] = (unsigned short)(u >> 16);
        al.u[i] = (unsigned short)(__float_as_uint(rem) >> 16);
      }
    }
    f32x4 acc[4];
#pragma unroll
    for (int ct = 0; ct < 4; ct++) {
      f32x4 z = {0.f, 0.f, 0.f, 0.f};
      z = __builtin_amdgcn_mfma_f32_16x16x32_bf16(ah.v, bh[ct].v, z, 0, 0, 0);
      z = __builtin_amdgcn_mfma_f32_16x16x32_bf16(ah.v, bl[ct].v, z, 0, 0, 0);
      z = __builtin_amdgcn_mfma_f32_16x16x32_bf16(al.v, bh[ct].v, z, 0, 0, 0);
      acc[ct] = z;
    }
    float o0[4], o1[4];
#pragma unroll
    for (int reg = 0; reg < 4; reg++) {
      int pr = base + q * 4 + reg;
      float2 ea = make_float2(0.f, 0.f);
      if (pr < NV) ea = eat2[pr];
      float s0 = 0.f, s1 = 0.f;
#pragma unroll
      for (int ct = 0; ct < 4; ct++) {
        float h = acc[ct][reg] + b1v[ct] + ea.x * w16v[ct] + ea.y * w17v[ct];
        h = fmaxf(h, 0.f);
        s0 += h * w2a[ct];
        s1 += h * w2b[ct];
      }
      o0[reg] = s0; o1[reg] = s1;
    }
#pragma unroll
    for (int m = 1; m < 16; m <<= 1) {
#pragma unroll
      for (int reg = 0; reg < 4; reg++) {
        o0[reg] += __shfl_xor(o0[reg], m, 64);
        o1[reg] += __shfl_xor(o1[reg], m, 64);
      }
    }
    if (lo4 == 0) {
#pragma unroll
      for (int reg = 0; reg < 4; reg++) {
        int pr = base + q * 4 + reg;
        if (pr < NV) {
          float v0 = bias20 + o0[reg], v1 = bias21 + o1[reg];
          ((float2*)(out + 2 * (size_t)NV))[pr] = make_float2(
              1.f / (1.f + __expf(-v0)), 1.f / (1.f + __expf(-v1)));
        }
      }
    }
  }
}

static inline size_t al64(size_t v) { return (v + 63) & ~(size_t)63; }

extern "C" void kernel_launch(void* const* d_in, const int* in_sizes, int n_in,
                              void* d_out, int out_size, void* d_ws, size_t ws_size,
                              hipStream_t stream) {
  const float* x     = (const float*)d_in[0];
  const int*   edges = (const int*)d_in[1];
  const float* eattr = (const float*)d_in[2];
  const void*  labels= d_in[3];
  const float* Wg    = (const float*)d_in[4];
  const float* atts  = (const float*)d_in[5];
  const float* attd  = (const float*)d_in[6];
  const float* We    = (const float*)d_in[7];
  const float* atte  = (const float*)d_in[8];
  const float* bg    = (const float*)d_in[9];
  const float* W1    = (const float*)d_in[10];
  const float* b1    = (const float*)d_in[11];
  const float* W2    = (const float*)d_in[12];
  const float* b2    = (const float*)d_in[13];
  float* out = (float*)d_out;
  const int NV = out_size / 4;
  const int* src = edges;
  const int* dst = edges + NE;

  char* w = (char*)d_ws;
  float* xh    = (float*)w;   w += al64((size_t)NN * 64);
  uint2* bins  = (uint2*)w;   w += al64((size_t)NE * 8);
  float2* eat2 = (float2*)w;  w += al64((size_t)NV * 8);
  float2* pka  = (float2*)w;  w += al64((size_t)NN * 8);
  float2* pkd  = (float2*)w;  w += al64((size_t)NN * 8);
  int* labN    = (int*)w;     w += al64((size_t)NN * 4);
  int* blkcnt  = (int*)w;     w += al64((size_t)NCB * NBK * 4);
  int* ssum    = (int*)w;     w += al64((size_t)NSTRIP * NBK * 4);
  int* total   = (int*)w;     w += al64((size_t)NBK * 4);
  int* bb      = (int*)w;     w += al64((size_t)(NBK + 1) * 4);
  int* cntc    = (int*)w;     w += al64((size_t)NCB * 4);
  int* offc    = (int*)w;     w += al64((size_t)(NCB + 1) * 4);
  int* cntw    = (int*)w;     w += al64((size_t)NWG * 4);
  int* offw    = (int*)w;     w += al64((size_t)NWG * 4);
  float* c01   = (float*)w;   w += 64;
  int* flags   = (int*)w;     w += 64;

  kdetect<<<1, 256, 0, stream>>>((const unsigned char*)labels, flags);
  klab<<<(NN + 255) / 256, 256, 0, stream>>>(labels, flags, labN);
  kc01<<<1, 64, 0, stream>>>(We, atte, c01);
  knodeA<<<(NN + 255) / 256, 256, 0, stream>>>(x, Wg, atts, attd, labN, pka, pkd);
  khist<<<NCB, 256, 0, stream>>>(src, dst, labN, blkcnt, cntw, cntc);
  kscanc1<<<dim3((NBK + 255) / 256, NSTRIP), 256, 0, stream>>>(blkcnt, ssum);
  kscanc2<<<(NBK + 255) / 256, 256, 0, stream>>>(ssum, total);
  kscan<<<1, 256, 0, stream>>>(total, bb, NBK);
  kscan<<<1, 256, 0, stream>>>(cntc, offc, NCB);
  kscanw<<<(NWG + 127) / 128, 128, 0, stream>>>(cntw, offc, offw);
  kscat<<<NCB, 256, 0, stream>>>(src, dst, eattr, pka, pkd, c01, bb, blkcnt, ssum,
                                 offw, bins, out, eat2, NV);
  kagg<<<NBK, 512, 0, stream>>>(bins, bb, x, Wg, bg, xh);
  if (NV > 0)
    kmlp<<<2048, 256, 0, stream>>>(eat2, xh, W1, b1, W2, b2, out, NV);
}

// Round 8
// 290.811 us; speedup vs baseline: 1.3073x; 1.0118x over previous
//
#include <hip/hip_runtime.h>

#define NN 100000
#define NE 3200000
#define CH 8192                        // edges per chunk
#define NCB ((NE + CH - 1) / CH)       // 391 chunks
#define THR 1024                       // threads per khist/kscat block
#define ITH (CH / THR)                 // 8 iterations
#define NBK ((NN + 63) >> 6)           // 1563 dst-buckets of 64 nodes
#define CAP 2560                       // payload capacity per sort round (5*512)
#define NWG (NE / 64)                  // 50000 wave-groups (exact)
#define NSTRIP 8
#define SLEN ((NCB + NSTRIP - 1) / NSTRIP)   // 49 chunks per strip

typedef __attribute__((ext_vector_type(8))) __bf16 bf16x8;
typedef __attribute__((ext_vector_type(4))) float f32x4;

union BF8 { unsigned short u[8]; bf16x8 v; };

// Detect label storage: int32 (harness-normalized) vs raw uint8 bool.
__global__ void kdetect(const unsigned char* __restrict__ lab8, int* __restrict__ flags) {
  __shared__ int tmp[256];
  int t = threadIdx.x;
  int s = 0;
  for (int i = t; i < 25000; i += 256) s += lab8[4 * i + 1];
  tmp[t] = s;
  __syncthreads();
  for (int d = 128; d > 0; d >>= 1) { if (t < d) tmp[t] += tmp[t + d]; __syncthreads(); }
  if (t == 0) flags[0] = (tmp[0] != 0) ? 1 : 0;
}

__global__ void klab(const void* __restrict__ lab, const int* __restrict__ flags,
                     int* __restrict__ labN) {
  int n = blockIdx.x * 256 + threadIdx.x;
  if (n >= NN) return;
  int v;
  if (flags[0]) v = ((const unsigned char*)lab)[n];
  else          v = ((const int*)lab)[n];
  labN[n] = (v != 0) ? 1 : 0;
}

// c01 = W_edge @ att_edge
__global__ void kc01(const float* __restrict__ We, const float* __restrict__ ae,
                     float* __restrict__ c01) {
  if (threadIdx.x == 0) {
    float c0 = 0.f, c1 = 0.f;
    for (int k = 0; k < 16; k++) { c0 += We[k] * ae[k]; c1 += We[16 + k] * ae[k]; }
    c01[0] = c0; c01[1] = c1;
  }
}

// Per-node attention partials PACKED with the label: pka={a_src,lab},
// pkd={a_dst,lab} -> kscat does 2x8B gathers instead of 4x4B.
__global__ void knodeA(const float* __restrict__ x, const float* __restrict__ Wg,
                       const float* __restrict__ atts, const float* __restrict__ attd,
                       const int* __restrict__ labN,
                       float2* __restrict__ pka, float2* __restrict__ pkd) {
  int n = blockIdx.x * 256 + threadIdx.x;
  if (n >= NN) return;
  float xi[5];
#pragma unroll
  for (int i = 0; i < 5; i++) xi[i] = x[n * 5 + i];
  float asum = 0.f, dsum = 0.f;
#pragma unroll
  for (int k = 0; k < 16; k++) {
    float acc = 0.f;
#pragma unroll
    for (int i = 0; i < 5; i++) acc += xi[i] * Wg[i * 16 + k];
    asum += acc * atts[k];
    dsum += acc * attd[k];
  }
  float lab = labN[n] ? 1.f : 0.f;
  pka[n] = make_float2(asum, lab);
  pkd[n] = make_float2(dsum, lab);
}

// Pass 1: per-chunk bucket histogram -> TRANSPOSED blkcnt[chunk][bucket]
// (contiguous per block) + per-wave-group valid counts + per-chunk counts.
__global__ __launch_bounds__(THR) void khist(const int* __restrict__ src,
                                             const int* __restrict__ dst,
                                             const int* __restrict__ labN,
                                             int* __restrict__ blkcnt,
                                             int* __restrict__ cntw,
                                             int* __restrict__ cntc) {
  __shared__ int hist[NBK];
  __shared__ int vsum;
  int tid = threadIdx.x, b = blockIdx.x;
  for (int i = tid; i < NBK; i += THR) hist[i] = 0;
  if (tid == 0) vsum = 0;
  __syncthreads();
  int lane = tid & 63, wid = tid >> 6;     // wid 0..15
  int wsum = 0;
  for (int it = 0; it < ITH; ++it) {
    int e = b * CH + it * THR + tid;
    int v = 0;
    if (e < NE) {
      int s = src[e], d = dst[e];
      atomicAdd(&hist[d >> 6], 1);
      v = labN[s] & labN[d];
    }
    unsigned long long m = __ballot(v != 0);
    int c = __popcll(m);
    if (lane == 0) {
      int wg = b * (CH / 64) + it * 16 + wid;
      if (wg < NWG) cntw[wg] = c;
      wsum += c;
    }
  }
  if (lane == 0) atomicAdd(&vsum, wsum);
  __syncthreads();
  int* row = blkcnt + (size_t)b * NBK;
  for (int i = tid; i < NBK; i += THR) row[i] = hist[i];
  if (tid == 0) cntc[b] = vsum;
}

// Column-scan phase 1: per (bucket, strip), serial exclusive scan over the
// strip's chunks in place; strip total -> ssum[strip][bucket]. Coalesced.
__global__ __launch_bounds__(256) void kscanc1(int* __restrict__ blkcnt,
                                               int* __restrict__ ssum) {
  int i = blockIdx.x * 256 + threadIdx.x;
  int st = blockIdx.y;
  if (i >= NBK) return;
  int c0 = st * SLEN, c1 = min(c0 + SLEN, NCB);
  int run = 0;
  for (int c = c0; c < c1; c++) {
    int* p = blkcnt + (size_t)c * NBK + i;
    int v = *p;
    *p = run;
    run += v;
  }
  ssum[st * NBK + i] = run;
}

// Column-scan phase 2: exclusive scan over the 8 strips per bucket + totals.
__global__ __launch_bounds__(256) void kscanc2(int* __restrict__ ssum,
                                               int* __restrict__ total) {
  int i = blockIdx.x * 256 + threadIdx.x;
  if (i >= NBK) return;
  int run = 0;
#pragma unroll
  for (int st = 0; st < NSTRIP; st++) {
    int v = ssum[st * NBK + i];
    ssum[st * NBK + i] = run;
    run += v;
  }
  total[i] = run;
}

// Fold bucket_base into ssum so kscat's cursor init reads 2 streams not 3.
__global__ __launch_bounds__(256) void kaddbb(int* __restrict__ ssum,
                                              const int* __restrict__ bb) {
  int i = blockIdx.x * 256 + threadIdx.x;
  if (i >= NBK) return;
  int v = bb[i];
#pragma unroll
  for (int st = 0; st < NSTRIP; st++) ssum[st * NBK + i] += v;
}

// generic single-block exclusive scan; also writes off[nb] = grand total
__global__ void kscan(const int* __restrict__ cnt, int* __restrict__ off, int nb) {
  __shared__ int tmp[256];
  __shared__ int carry;
  int t = threadIdx.x;
  if (t == 0) carry = 0;
  __syncthreads();
  for (int base = 0; base < nb; base += 256) {
    int i = base + t;
    int v = (i < nb) ? cnt[i] : 0;
    tmp[t] = v;
    __syncthreads();
    for (int d = 1; d < 256; d <<= 1) {
      int add = (t >= d) ? tmp[t - d] : 0;
      __syncthreads();
      tmp[t] += add;
      __syncthreads();
    }
    if (i < nb) off[i] = carry + tmp[t] - v;
    __syncthreads();
    if (t == 0) carry += tmp[255];
    __syncthreads();
  }
  if (t == 0) off[nb] = carry;
}

// Per-chunk scan of the 128 wave-group counts -> absolute offsets offw.
__global__ __launch_bounds__(128) void kscanw(const int* __restrict__ cntw,
                                              const int* __restrict__ offc,
                                              int* __restrict__ offw) {
  int b = blockIdx.x, t = threadIdx.x;
  __shared__ int a[128];
  int wg = b * 128 + t;
  int val = (wg < NWG) ? cntw[wg] : 0;
  a[t] = val;
  __syncthreads();
  for (int d = 1; d < 128; d <<= 1) {
    int x = (t >= d) ? a[t - d] : 0;
    __syncthreads();
    a[t] += x;
    __syncthreads();
  }
  if (wg < NWG) offw[wg] = offc[b] + a[t] - val;
}

__device__ __forceinline__ void scat_body(
    int e, int b, int it, int lane, int wid,
    const int* __restrict__ src, const int* __restrict__ dst,
    const float* __restrict__ eattr,
    const float2* __restrict__ pka, const float2* __restrict__ pkd,
    float c0, float c1, int* cur, const int* __restrict__ offw,
    uint2* __restrict__ bins, float* __restrict__ out,
    float2* __restrict__ eat2, int NV) {
  int s = src[e], d = dst[e];
  float2 ea = ((const float2*)eattr)[e];
  float2 ga = pka[s], gd = pkd[d];
  float al = ga.x + gd.x + ea.x * c0 + ea.y * c1;
  al = (al > 0.f) ? al : 0.2f * al;
  float exv = __expf(al);
  int pos = atomicAdd(&cur[d >> 6], 1);
  uint2 pl;
  pl.x = ((unsigned)s << 6) | (unsigned)(d & 63);
  pl.y = __float_as_uint(exv);
  bins[pos] = pl;
  int v = (ga.y != 0.f) && (gd.y != 0.f);
  unsigned long long m = __ballot(v);
  if (v) {
    int wg = b * (CH / 64) + it * 16 + wid;    // == e/64, matches khist cntw
    int p = offw[wg] + __popcll(m & ((1ull << lane) - 1ull));
    if (p < NV) {
      out[p] = (float)s;
      out[NV + p] = (float)d;
      eat2[p] = ea;
    }
  }
}

// Pass 3: CH=8192 (round-4's 5.2-payload bucket-runs -> ~124MB write merging)
// x 1024 threads (round-7's 6.3K-wave parallelism: 391 blocks x 16 waves, all
// co-resident). Full chunks take an unrolled guard-free path so 8 independent
// iterations pipeline (16 outstanding gathers per wave). XCD-bijective chunk
// swizzle keeps adjacent chunks on one XCD for L2 write-merging of shared
// bucket-run boundary lines.
__global__ __launch_bounds__(THR) void kscat(
    const int* __restrict__ src, const int* __restrict__ dst,
    const float* __restrict__ eattr,
    const float2* __restrict__ pka, const float2* __restrict__ pkd,
    const float* __restrict__ c01,
    const int* __restrict__ blkcnt, const int* __restrict__ ssum,
    const int* __restrict__ offw,
    uint2* __restrict__ bins, float* __restrict__ out,
    float2* __restrict__ eat2, int NV) {
  __shared__ int cur[NBK];
  int ob = blockIdx.x, tid = threadIdx.x;
  // bijective XCD swizzle over NCB=391 (q=48, r=7)
  int xcd = ob & 7, loc = ob >> 3;
  const int q = NCB >> 3, r = NCB & 7;
  int b = ((xcd < r) ? xcd * (q + 1) : r * (q + 1) + (xcd - r) * q) + loc;
  const int* bc = blkcnt + (size_t)b * NBK;
  const int* ss = ssum + (size_t)(b / SLEN) * NBK;   // includes bucket_base
  for (int i = tid; i < NBK; i += THR) cur[i] = ss[i] + bc[i];
  float c0 = c01[0], c1 = c01[1];
  __syncthreads();
  int lane = tid & 63, wid = tid >> 6;
  if (b * CH + CH <= NE) {
#pragma unroll
    for (int it = 0; it < ITH; ++it)
      scat_body(b * CH + it * THR + tid, b, it, lane, wid, src, dst, eattr,
                pka, pkd, c0, c1, cur, offw, bins, out, eat2, NV);
  } else {
    for (int it = 0; it < ITH; ++it) {
      int e = b * CH + it * THR + tid;
      if (e >= NE) break;                    // tail aligns to THR: uniform
      scat_body(e, b, it, lane, wid, src, dst, eattr,
                pka, pkd, c0, c1, cur, offw, bins, out, eat2, NV);
    }
  }
}

// Pass 4: one block per 64-node bucket. Counting-sort the bucket's payloads by
// local node in LDS (int atomics only), then walk each node's contiguous run
// with 16 lanes/node accumulating in REGISTERS. Fused norm+bias+relu.
__global__ __launch_bounds__(512) void kagg(
    const uint2* __restrict__ bins, const int* __restrict__ bucket_base,
    const float* __restrict__ x, const float* __restrict__ Wg,
    const float* __restrict__ bg, float* __restrict__ xh) {
  __shared__ uint2 pay[CAP];
  __shared__ int cnt[64], inc[64], cur[64];
  __shared__ float sWg[80], sbg[16];
  int k = blockIdx.x, tid = threadIdx.x;
  if (tid < 80) sWg[tid] = Wg[tid];
  else if (tid < 96) sbg[tid - 80] = bg[tid - 80];
  int start = bucket_base[k], end = bucket_base[k + 1];
  int node0 = k << 6;
  int c = tid & 15, g = tid >> 4;     // g: 0..31
  __syncthreads();
  float w0 = sWg[c], w1 = sWg[16 + c], w2 = sWg[32 + c], w3 = sWg[48 + c], w4 = sWg[64 + c];
  float acc[2] = {0.f, 0.f}, den[2] = {0.f, 0.f};
  for (int cb = start; cb < end; cb += CAP) {        // single round in practice
    int n = min(end - cb, CAP);
    if (tid < 64) cnt[tid] = 0;
    __syncthreads();
    uint2 st0, st1, st2, st3, st4;                   // register-staged payloads
    {
      int i;
      i = tid;          if (i < n) { st0 = bins[cb + i]; atomicAdd(&cnt[st0.x & 63], 1); }
      i = tid + 512;    if (i < n) { st1 = bins[cb + i]; atomicAdd(&cnt[st1.x & 63], 1); }
      i = tid + 1024;   if (i < n) { st2 = bins[cb + i]; atomicAdd(&cnt[st2.x & 63], 1); }
      i = tid + 1536;   if (i < n) { st3 = bins[cb + i]; atomicAdd(&cnt[st3.x & 63], 1); }
      i = tid + 2048;   if (i < n) { st4 = bins[cb + i]; atomicAdd(&cnt[st4.x & 63], 1); }
    }
    __syncthreads();
    if (tid < 64) inc[tid] = cnt[tid];
    __syncthreads();
    for (int d = 1; d < 64; d <<= 1) {
      int v = 0;
      if (tid >= d && tid < 64) v = inc[tid - d];
      __syncthreads();
      if (tid < 64) inc[tid] += v;
      __syncthreads();
    }
    if (tid < 64) cur[tid] = inc[tid] - cnt[tid];
    __syncthreads();
    {
      int i;
      i = tid;          if (i < n) pay[atomicAdd(&cur[st0.x & 63], 1)] = st0;
      i = tid + 512;    if (i < n) pay[atomicAdd(&cur[st1.x & 63], 1)] = st1;
      i = tid + 1024;   if (i < n) pay[atomicAdd(&cur[st2.x & 63], 1)] = st2;
      i = tid + 1536;   if (i < n) pay[atomicAdd(&cur[st3.x & 63], 1)] = st3;
      i = tid + 2048;   if (i < n) pay[atomicAdd(&cur[st4.x & 63], 1)] = st4;
    }
    __syncthreads();
#pragma unroll
    for (int p = 0; p < 2; ++p) {
      int nd = p * 32 + g;
      int re = inc[nd], rs = re - cnt[nd];
      float a = 0.f, ds = 0.f;
      for (int idx = rs; idx < re; ++idx) {
        uint2 pl = pay[idx];                         // broadcast ds_read_b64
        int s = (int)(pl.x >> 6);
        float exv = __uint_as_float(pl.y);
        const float* xp = x + s * 5;                 // broadcast within group
        float h = xp[0] * w0 + xp[1] * w1 + xp[2] * w2 + xp[3] * w3 + xp[4] * w4;
        a += h * exv;
        ds += exv;
      }
      acc[p] += a; den[p] += ds;
    }
    __syncthreads();
  }
#pragma unroll
  for (int p = 0; p < 2; ++p) {
    int node = node0 + p * 32 + g;
    if (node < NN) {
      float dn = fmaxf(den[p], 1e-30f);
      float v = acc[p] / dn + sbg[c];
      xh[node * 16 + c] = (v > 0.f) ? v : 0.f;
    }
  }
}

// edge MLP via MFMA (unchanged). Hidden GEMM [NV,32]x[32,64] with trunc hi/lo
// bf16 split (AhBh+AhBl+AlBh); A-fragments gather directly from xh; W1
// B-fragments live in VGPRs; fp32 epilogue + shfl reduce.
__global__ __launch_bounds__(256) void kmlp(
    const float2* __restrict__ eat2, const float* __restrict__ xh,
    const float* __restrict__ W1, const float* __restrict__ b1,
    const float* __restrict__ W2, const float* __restrict__ b2,
    float* __restrict__ out, int NV) {
  int tid = threadIdx.x;
  int lane = tid & 63, wid = tid >> 6;
  int lo4 = lane & 15, q = lane >> 4;

  BF8 bh[4], bl[4];
#pragma unroll
  for (int ct = 0; ct < 4; ct++) {
    int col = ct * 16 + lo4;
#pragma unroll
    for (int i = 0; i < 8; i++) {
      int k = q * 8 + i;
      int r = (k < 16) ? k : (k + 2);
      float w = W1[r * 64 + col];
      unsigned u = __float_as_uint(w);
      float rem = w - __uint_as_float(u & 0xffff0000u);
      bh[ct].u[i] = (unsigned short)(u >> 16);
      bl[ct].u[i] = (unsigned short)(__float_as_uint(rem) >> 16);
    }
  }
  float b1v[4], w16v[4], w17v[4], w2a[4], w2b[4];
#pragma unroll
  for (int ct = 0; ct < 4; ct++) {
    int j = ct * 16 + lo4;
    b1v[ct] = b1[j];
    w16v[ct] = W1[16 * 64 + j];
    w17v[ct] = W1[17 * 64 + j];
    w2a[ct] = W2[j * 2 + 0];
    w2b[ct] = W2[j * 2 + 1];
  }
  float bias20 = b2[0], bias21 = b2[1];

  int nwaves = gridDim.x * 4;
  int ntiles = (NV + 15) >> 4;
  for (int tb = blockIdx.x * 4 + wid; tb < ntiles; tb += nwaves) {
    int base = tb * 16;
    BF8 ah, al;
    {
      int p = base + lo4;
      float vals[8] = {0.f, 0.f, 0.f, 0.f, 0.f, 0.f, 0.f, 0.f};
      if (p < NV) {
        int node = (int)out[((q < 2) ? 0 : NV) + p];
        const float4* xp = (const float4*)(xh + node * 16 + (q & 1) * 8);
        float4 f0 = xp[0], f1 = xp[1];
        vals[0] = f0.x; vals[1] = f0.y; vals[2] = f0.z; vals[3] = f0.w;
        vals[4] = f1.x; vals[5] = f1.y; vals[6] = f1.z; vals[7] = f1.w;
      }
#pragma unroll
      for (int i = 0; i < 8; i++) {
        unsigned u = __float_as_uint(vals[i]);
        float rem = vals[i] - __uint_as_float(u & 0xffff0000u);
        ah.u[i] = (unsigned short)(u >> 16);
        al.u[i] = (unsigned short)(__float_as_uint(rem) >> 16);
      }
    }
    f32x4 acc[4];
#pragma unroll
    for (int ct = 0; ct < 4; ct++) {
      f32x4 z = {0.f, 0.f, 0.f, 0.f};
      z = __builtin_amdgcn_mfma_f32_16x16x32_bf16(ah.v, bh[ct].v, z, 0, 0, 0);
      z = __builtin_amdgcn_mfma_f32_16x16x32_bf16(ah.v, bl[ct].v, z, 0, 0, 0);
      z = __builtin_amdgcn_mfma_f32_16x16x32_bf16(al.v, bh[ct].v, z, 0, 0, 0);
      acc[ct] = z;
    }
    float o0[4], o1[4];
#pragma unroll
    for (int reg = 0; reg < 4; reg++) {
      int pr = base + q * 4 + reg;
      float2 ea = make_float2(0.f, 0.f);
      if (pr < NV) ea = eat2[pr];
      float s0 = 0.f, s1 = 0.f;
#pragma unroll
      for (int ct = 0; ct < 4; ct++) {
        float h = acc[ct][reg] + b1v[ct] + ea.x * w16v[ct] + ea.y * w17v[ct];
        h = fmaxf(h, 0.f);
        s0 += h * w2a[ct];
        s1 += h * w2b[ct];
      }
      o0[reg] = s0; o1[reg] = s1;
    }
#pragma unroll
    for (int m = 1; m < 16; m <<= 1) {
#pragma unroll
      for (int reg = 0; reg < 4; reg++) {
        o0[reg] += __shfl_xor(o0[reg], m, 64);
        o1[reg] += __shfl_xor(o1[reg], m, 64);
      }
    }
    if (lo4 == 0) {
#pragma unroll
      for (int reg = 0; reg < 4; reg++) {
        int pr = base + q * 4 + reg;
        if (pr < NV) {
          float v0 = bias20 + o0[reg], v1 = bias21 + o1[reg];
          ((float2*)(out + 2 * (size_t)NV))[pr] = make_float2(
              1.f / (1.f + __expf(-v0)), 1.f / (1.f + __expf(-v1)));
        }
      }
    }
  }
}

static inline size_t al64(size_t v) { return (v + 63) & ~(size_t)63; }

extern "C" void kernel_launch(void* const* d_in, const int* in_sizes, int n_in,
                              void* d_out, int out_size, void* d_ws, size_t ws_size,
                              hipStream_t stream) {
  const float* x     = (const float*)d_in[0];
  const int*   edges = (const int*)d_in[1];
  const float* eattr = (const float*)d_in[2];
  const void*  labels= d_in[3];
  const float* Wg    = (const float*)d_in[4];
  const float* atts  = (const float*)d_in[5];
  const float* attd  = (const float*)d_in[6];
  const float* We    = (const float*)d_in[7];
  const float* atte  = (const float*)d_in[8];
  const float* bg    = (const float*)d_in[9];
  const float* W1    = (const float*)d_in[10];
  const float* b1    = (const float*)d_in[11];
  const float* W2    = (const float*)d_in[12];
  const float* b2    = (const float*)d_in[13];
  float* out = (float*)d_out;
  const int NV = out_size / 4;
  const int* src = edges;
  const int* dst = edges + NE;

  char* w = (char*)d_ws;
  float* xh    = (float*)w;   w += al64((size_t)NN * 64);
  uint2* bins  = (uint2*)w;   w += al64((size_t)NE * 8);
  float2* eat2 = (float2*)w;  w += al64((size_t)NV * 8);
  float2* pka  = (float2*)w;  w += al64((size_t)NN * 8);
  float2* pkd  = (float2*)w;  w += al64((size_t)NN * 8);
  int* labN    = (int*)w;     w += al64((size_t)NN * 4);
  int* blkcnt  = (int*)w;     w += al64((size_t)NCB * NBK * 4);
  int* ssum    = (int*)w;     w += al64((size_t)NSTRIP * NBK * 4);
  int* total   = (int*)w;     w += al64((size_t)NBK * 4);
  int* bb      = (int*)w;     w += al64((size_t)(NBK + 1) * 4);
  int* cntc    = (int*)w;     w += al64((size_t)NCB * 4);
  int* offc    = (int*)w;     w += al64((size_t)(NCB + 1) * 4);
  int* cntw    = (int*)w;     w += al64((size_t)NWG * 4);
  int* offw    = (int*)w;     w += al64((size_t)NWG * 4);
  float* c01   = (float*)w;   w += 64;
  int* flags   = (int*)w;     w += 64;

  kdetect<<<1, 256, 0, stream>>>((const unsigned char*)labels, flags);
  klab<<<(NN + 255) / 256, 256, 0, stream>>>(labels, flags, labN);
  kc01<<<1, 64, 0, stream>>>(We, atte, c01);
  knodeA<<<(NN + 255) / 256, 256, 0, stream>>>(x, Wg, atts, attd, labN, pka, pkd);
  khist<<<NCB, THR, 0, stream>>>(src, dst, labN, blkcnt, cntw, cntc);
  kscanc1<<<dim3((NBK + 255) / 256, NSTRIP), 256, 0, stream>>>(blkcnt, ssum);
  kscanc2<<<(NBK + 255) / 256, 256, 0, stream>>>(ssum, total);
  kscan<<<1, 256, 0, stream>>>(total, bb, NBK);
  kaddbb<<<(NBK + 255) / 256, 256, 0, stream>>>(ssum, bb);
  kscan<<<1, 256, 0, stream>>>(cntc, offc, NCB);
  kscanw<<<NCB, 128, 0, stream>>>(cntw, offc, offw);
  kscat<<<NCB, THR, 0, stream>>>(src, dst, eattr, pka, pkd, c01, blkcnt, ssum,
                                 offw, bins, out, eat2, NV);
  kagg<<<NBK, 512, 0, stream>>>(bins, bb, x, Wg, bg, xh);
  if (NV > 0)
    kmlp<<<2048, 256, 0, stream>>>(eat2, xh, W1, b1, W2, b2, out, NV);
}

// Round 9
// 280.351 us; speedup vs baseline: 1.3561x; 1.0373x over previous
//
#include <hip/hip_runtime.h>

#define NN 100000
#define NE 3200000
#define CH 8192                        // edges per chunk
#define NCB ((NE + CH - 1) / CH)       // 391 chunks
#define THR 1024                       // threads per khist/kscat block
#define ITH (CH / THR)                 // 8 iterations
#define NBK ((NN + 63) >> 6)           // 1563 dst-buckets of 64 nodes
#define CAP 2560                       // payload capacity per sort round (5*512)
#define NWG (NE / 64)                  // 50000 wave-groups (exact)
#define NSTRIP 8
#define SLEN ((NCB + NSTRIP - 1) / NSTRIP)   // 49 chunks per strip

typedef __attribute__((ext_vector_type(8))) __bf16 bf16x8;
typedef __attribute__((ext_vector_type(4))) float f32x4;

union BF8 { unsigned short u[8]; bf16x8 v; };

// Detect label storage: int32 (harness-normalized) vs raw uint8 bool.
__global__ void kdetect(const unsigned char* __restrict__ lab8, int* __restrict__ flags) {
  __shared__ int tmp[256];
  int t = threadIdx.x;
  int s = 0;
  for (int i = t; i < 25000; i += 256) s += lab8[4 * i + 1];
  tmp[t] = s;
  __syncthreads();
  for (int d = 128; d > 0; d >>= 1) { if (t < d) tmp[t] += tmp[t + d]; __syncthreads(); }
  if (t == 0) flags[0] = (tmp[0] != 0) ? 1 : 0;
}

__global__ void klab(const void* __restrict__ lab, const int* __restrict__ flags,
                     int* __restrict__ labN) {
  int n = blockIdx.x * 256 + threadIdx.x;
  if (n >= NN) return;
  int v;
  if (flags[0]) v = ((const unsigned char*)lab)[n];
  else          v = ((const int*)lab)[n];
  labN[n] = (v != 0) ? 1 : 0;
}

// c01 = W_edge @ att_edge
__global__ void kc01(const float* __restrict__ We, const float* __restrict__ ae,
                     float* __restrict__ c01) {
  if (threadIdx.x == 0) {
    float c0 = 0.f, c1 = 0.f;
    for (int k = 0; k < 16; k++) { c0 += We[k] * ae[k]; c1 += We[16 + k] * ae[k]; }
    c01[0] = c0; c01[1] = c1;
  }
}

// Per-node attention partials PACKED with the label: pka={a_src,lab},
// pkd={a_dst,lab} -> kscat does 2x8B gathers instead of 4x4B.
__global__ void knodeA(const float* __restrict__ x, const float* __restrict__ Wg,
                       const float* __restrict__ atts, const float* __restrict__ attd,
                       const int* __restrict__ labN,
                       float2* __restrict__ pka, float2* __restrict__ pkd) {
  int n = blockIdx.x * 256 + threadIdx.x;
  if (n >= NN) return;
  float xi[5];
#pragma unroll
  for (int i = 0; i < 5; i++) xi[i] = x[n * 5 + i];
  float asum = 0.f, dsum = 0.f;
#pragma unroll
  for (int k = 0; k < 16; k++) {
    float acc = 0.f;
#pragma unroll
    for (int i = 0; i < 5; i++) acc += xi[i] * Wg[i * 16 + k];
    asum += acc * atts[k];
    dsum += acc * attd[k];
  }
  float lab = labN[n] ? 1.f : 0.f;
  pka[n] = make_float2(asum, lab);
  pkd[n] = make_float2(dsum, lab);
}

// Pass 1: per-chunk bucket histogram -> TRANSPOSED blkcnt[chunk][bucket]
// (contiguous per block) + per-wave-group valid counts + per-chunk counts.
__global__ __launch_bounds__(THR) void khist(const int* __restrict__ src,
                                             const int* __restrict__ dst,
                                             const int* __restrict__ labN,
                                             int* __restrict__ blkcnt,
                                             int* __restrict__ cntw,
                                             int* __restrict__ cntc) {
  __shared__ int hist[NBK];
  __shared__ int vsum;
  int tid = threadIdx.x, b = blockIdx.x;
  for (int i = tid; i < NBK; i += THR) hist[i] = 0;
  if (tid == 0) vsum = 0;
  __syncthreads();
  int lane = tid & 63, wid = tid >> 6;     // wid 0..15
  int wsum = 0;
  for (int it = 0; it < ITH; ++it) {
    int e = b * CH + it * THR + tid;
    int v = 0;
    if (e < NE) {
      int s = src[e], d = dst[e];
      atomicAdd(&hist[d >> 6], 1);
      v = labN[s] & labN[d];
    }
    unsigned long long m = __ballot(v != 0);
    int c = __popcll(m);
    if (lane == 0) {
      int wg = b * (CH / 64) + it * 16 + wid;
      if (wg < NWG) cntw[wg] = c;
      wsum += c;
    }
  }
  if (lane == 0) atomicAdd(&vsum, wsum);
  __syncthreads();
  int* row = blkcnt + (size_t)b * NBK;
  for (int i = tid; i < NBK; i += THR) row[i] = hist[i];
  if (tid == 0) cntc[b] = vsum;
}

// Column-scan phase 1: per (bucket, strip), serial exclusive scan over the
// strip's chunks in place; strip total -> ssum[strip][bucket]. Coalesced.
__global__ __launch_bounds__(256) void kscanc1(int* __restrict__ blkcnt,
                                               int* __restrict__ ssum) {
  int i = blockIdx.x * 256 + threadIdx.x;
  int st = blockIdx.y;
  if (i >= NBK) return;
  int c0 = st * SLEN, c1 = min(c0 + SLEN, NCB);
  int run = 0;
  for (int c = c0; c < c1; c++) {
    int* p = blkcnt + (size_t)c * NBK + i;
    int v = *p;
    *p = run;
    run += v;
  }
  ssum[st * NBK + i] = run;
}

// Column-scan phase 2: exclusive scan over the 8 strips per bucket + totals.
__global__ __launch_bounds__(256) void kscanc2(int* __restrict__ ssum,
                                               int* __restrict__ total) {
  int i = blockIdx.x * 256 + threadIdx.x;
  if (i >= NBK) return;
  int run = 0;
#pragma unroll
  for (int st = 0; st < NSTRIP; st++) {
    int v = ssum[st * NBK + i];
    ssum[st * NBK + i] = run;
    run += v;
  }
  total[i] = run;
}

// Fold bucket_base into ssum so kscat's cursor init reads 2 streams not 3.
__global__ __launch_bounds__(256) void kaddbb(int* __restrict__ ssum,
                                              const int* __restrict__ bb) {
  int i = blockIdx.x * 256 + threadIdx.x;
  if (i >= NBK) return;
  int v = bb[i];
#pragma unroll
  for (int st = 0; st < NSTRIP; st++) ssum[st * NBK + i] += v;
}

// generic single-block exclusive scan; also writes off[nb] = grand total
__global__ void kscan(const int* __restrict__ cnt, int* __restrict__ off, int nb) {
  __shared__ int tmp[256];
  __shared__ int carry;
  int t = threadIdx.x;
  if (t == 0) carry = 0;
  __syncthreads();
  for (int base = 0; base < nb; base += 256) {
    int i = base + t;
    int v = (i < nb) ? cnt[i] : 0;
    tmp[t] = v;
    __syncthreads();
    for (int d = 1; d < 256; d <<= 1) {
      int add = (t >= d) ? tmp[t - d] : 0;
      __syncthreads();
      tmp[t] += add;
      __syncthreads();
    }
    if (i < nb) off[i] = carry + tmp[t] - v;
    __syncthreads();
    if (t == 0) carry += tmp[255];
    __syncthreads();
  }
  if (t == 0) off[nb] = carry;
}

// Per-chunk scan of the 128 wave-group counts -> absolute offsets offw.
__global__ __launch_bounds__(128) void kscanw(const int* __restrict__ cntw,
                                              const int* __restrict__ offc,
                                              int* __restrict__ offw) {
  int b = blockIdx.x, t = threadIdx.x;
  __shared__ int a[128];
  int wg = b * 128 + t;
  int val = (wg < NWG) ? cntw[wg] : 0;
  a[t] = val;
  __syncthreads();
  for (int d = 1; d < 128; d <<= 1) {
    int x = (t >= d) ? a[t - d] : 0;
    __syncthreads();
    a[t] += x;
    __syncthreads();
  }
  if (wg < NWG) offw[wg] = offc[b] + a[t] - val;
}

// Pass 3 (rewritten): sort-then-stream. Round-8 PMC showed the random
// atomic-cursor scatter is bound by partial-line thrash (WRITE 167MB for a
// 25.6MB dense permutation) + 64B-transaction-per-8B-store serialization.
// New structure per 8192-edge chunk:
//   P1 compute payloads -> registers, LDS histogram, valid-compaction (as is)
//   P2 block scan of hist[1563] (pair + Hillis-Steele over 1024)
//   P3 scatter payloads into LDS by bucket (LDS atomics)
//   P4 write out in SORTED order: consecutive threads -> consecutive global
//      slots; a wave emits ~12 contiguous segments instead of 64 random 8B
//      stores, and each line's stores arrive in one burst from one block.
__global__ __launch_bounds__(THR) void kscat(
    const int* __restrict__ src, const int* __restrict__ dst,
    const float* __restrict__ eattr,
    const float2* __restrict__ pka, const float2* __restrict__ pkd,
    const float* __restrict__ c01,
    const int* __restrict__ blkcnt, const int* __restrict__ ssum,
    const int* __restrict__ offw,
    uint2* __restrict__ bins, float* __restrict__ out,
    float2* __restrict__ eat2, int NV) {
  __shared__ uint2 pay[CH];                 // 64 KB sorted payloads
  __shared__ unsigned short pbk[CH];        // 16 KB bucket ids
  __shared__ int hist[2048];                // 8 KB raw counts (NBK used)
  __shared__ int ps[1024];                  // 4 KB pair-sum scan
  __shared__ int lcur[2048];                // 8 KB LDS cursors (= lscan init)
  __shared__ int goff[NBK];                 // 6.25 KB  global_base - lscan
  int b = blockIdx.x, tid = threadIdx.x;
  for (int i = tid; i < 2048; i += THR) hist[i] = 0;
  float c0 = c01[0], c1 = c01[1];
  const int* bc = blkcnt + (size_t)b * NBK;
  const int* ss = ssum + (size_t)(b / SLEN) * NBK;   // includes bucket_base
  __syncthreads();
  int lane = tid & 63, wid = tid >> 6;
  uint2 st[ITH];
  unsigned short sb[ITH];
  // P1: compute + stage + hist + ordered valid-compaction
#pragma unroll
  for (int it = 0; it < ITH; ++it) {
    int e = b * CH + it * THR + tid;
    int v = 0;
    int s = 0, d = 0;
    float2 ea;
    if (e < NE) {
      s = src[e]; d = dst[e];
      ea = ((const float2*)eattr)[e];
      float2 ga = pka[s], gd = pkd[d];
      float al = ga.x + gd.x + ea.x * c0 + ea.y * c1;
      al = (al > 0.f) ? al : 0.2f * al;
      float exv = __expf(al);
      int bk = d >> 6;
      atomicAdd(&hist[bk], 1);
      st[it].x = ((unsigned)s << 6) | (unsigned)(d & 63);
      st[it].y = __float_as_uint(exv);
      sb[it] = (unsigned short)bk;
      v = (ga.y != 0.f) && (gd.y != 0.f);
    } else {
      sb[it] = 0xffffu;
    }
    unsigned long long m = __ballot(v);
    if (v) {
      int wg = b * (CH / 64) + it * 16 + wid;   // == e/64, matches khist cntw
      int p = offw[wg] + __popcll(m & ((1ull << lane) - 1ull));
      if (p < NV) {
        out[p] = (float)s;
        out[NV + p] = (float)d;
        eat2[p] = ea;
      }
    }
  }
  __syncthreads();
  // P2: exclusive scan of hist[0..2047]; thread t owns slots 2t, 2t+1
  int h0 = hist[2 * tid], h1 = hist[2 * tid + 1];
  ps[tid] = h0 + h1;
  __syncthreads();
  for (int d = 1; d < 1024; d <<= 1) {
    int v = (tid >= d) ? ps[tid - d] : 0;
    __syncthreads();
    ps[tid] += v;
    __syncthreads();
  }
  int epair = (tid > 0) ? ps[tid - 1] : 0;    // exclusive pair prefix
  int l0 = epair, l1 = epair + h0;
  lcur[2 * tid] = l0;
  lcur[2 * tid + 1] = l1;
  {
    int i0 = 2 * tid, i1 = 2 * tid + 1;
    if (i0 < NBK) goff[i0] = ss[i0] + bc[i0] - l0;
    if (i1 < NBK) goff[i1] = ss[i1] + bc[i1] - l1;
  }
  __syncthreads();
  // P3: scatter payloads into LDS, bucket-sorted
#pragma unroll
  for (int it = 0; it < ITH; ++it) {
    if (sb[it] != 0xffffu) {
      int pos = atomicAdd(&lcur[sb[it]], 1);
      pay[pos] = st[it];
      pbk[pos] = sb[it];
    }
  }
  __syncthreads();
  // P4: sorted, segment-contiguous write-out
  int n = ps[1023];                           // real payloads this chunk
  for (int j = tid; j < n; j += THR) {
    int i = pbk[j];
    bins[goff[i] + j] = pay[j];
  }
}

// Pass 4: one block per 64-node bucket. Counting-sort the bucket's payloads by
// local node in LDS (int atomics only), then walk each node's contiguous run
// with 16 lanes/node accumulating in REGISTERS. Fused norm+bias+relu.
__global__ __launch_bounds__(512) void kagg(
    const uint2* __restrict__ bins, const int* __restrict__ bucket_base,
    const float* __restrict__ x, const float* __restrict__ Wg,
    const float* __restrict__ bg, float* __restrict__ xh) {
  __shared__ uint2 pay[CAP];
  __shared__ int cnt[64], inc[64], cur[64];
  __shared__ float sWg[80], sbg[16];
  int k = blockIdx.x, tid = threadIdx.x;
  if (tid < 80) sWg[tid] = Wg[tid];
  else if (tid < 96) sbg[tid - 80] = bg[tid - 80];
  int start = bucket_base[k], end = bucket_base[k + 1];
  int node0 = k << 6;
  int c = tid & 15, g = tid >> 4;     // g: 0..31
  __syncthreads();
  float w0 = sWg[c], w1 = sWg[16 + c], w2 = sWg[32 + c], w3 = sWg[48 + c], w4 = sWg[64 + c];
  float acc[2] = {0.f, 0.f}, den[2] = {0.f, 0.f};
  for (int cb = start; cb < end; cb += CAP) {        // single round in practice
    int n = min(end - cb, CAP);
    if (tid < 64) cnt[tid] = 0;
    __syncthreads();
    uint2 st0, st1, st2, st3, st4;                   // register-staged payloads
    {
      int i;
      i = tid;          if (i < n) { st0 = bins[cb + i]; atomicAdd(&cnt[st0.x & 63], 1); }
      i = tid + 512;    if (i < n) { st1 = bins[cb + i]; atomicAdd(&cnt[st1.x & 63], 1); }
      i = tid + 1024;   if (i < n) { st2 = bins[cb + i]; atomicAdd(&cnt[st2.x & 63], 1); }
      i = tid + 1536;   if (i < n) { st3 = bins[cb + i]; atomicAdd(&cnt[st3.x & 63], 1); }
      i = tid + 2048;   if (i < n) { st4 = bins[cb + i]; atomicAdd(&cnt[st4.x & 63], 1); }
    }
    __syncthreads();
    if (tid < 64) inc[tid] = cnt[tid];
    __syncthreads();
    for (int d = 1; d < 64; d <<= 1) {
      int v = 0;
      if (tid >= d && tid < 64) v = inc[tid - d];
      __syncthreads();
      if (tid < 64) inc[tid] += v;
      __syncthreads();
    }
    if (tid < 64) cur[tid] = inc[tid] - cnt[tid];
    __syncthreads();
    {
      int i;
      i = tid;          if (i < n) pay[atomicAdd(&cur[st0.x & 63], 1)] = st0;
      i = tid + 512;    if (i < n) pay[atomicAdd(&cur[st1.x & 63], 1)] = st1;
      i = tid + 1024;   if (i < n) pay[atomicAdd(&cur[st2.x & 63], 1)] = st2;
      i = tid + 1536;   if (i < n) pay[atomicAdd(&cur[st3.x & 63], 1)] = st3;
      i = tid + 2048;   if (i < n) pay[atomicAdd(&cur[st4.x & 63], 1)] = st4;
    }
    __syncthreads();
#pragma unroll
    for (int p = 0; p < 2; ++p) {
      int nd = p * 32 + g;
      int re = inc[nd], rs = re - cnt[nd];
      float a = 0.f, ds = 0.f;
      for (int idx = rs; idx < re; ++idx) {
        uint2 pl = pay[idx];                         // broadcast ds_read_b64
        int s = (int)(pl.x >> 6);
        float exv = __uint_as_float(pl.y);
        const float* xp = x + s * 5;                 // broadcast within group
        float h = xp[0] * w0 + xp[1] * w1 + xp[2] * w2 + xp[3] * w3 + xp[4] * w4;
        a += h * exv;
        ds += exv;
      }
      acc[p] += a; den[p] += ds;
    }
    __syncthreads();
  }
#pragma unroll
  for (int p = 0; p < 2; ++p) {
    int node = node0 + p * 32 + g;
    if (node < NN) {
      float dn = fmaxf(den[p], 1e-30f);
      float v = acc[p] / dn + sbg[c];
      xh[node * 16 + c] = (v > 0.f) ? v : 0.f;
    }
  }
}

// edge MLP via MFMA (unchanged). Hidden GEMM [NV,32]x[32,64] with trunc hi/lo
// bf16 split (AhBh+AhBl+AlBh); A-fragments gather directly from xh; W1
// B-fragments live in VGPRs; fp32 epilogue + shfl reduce.
__global__ __launch_bounds__(256) void kmlp(
    const float2* __restrict__ eat2, const float* __restrict__ xh,
    const float* __restrict__ W1, const float* __restrict__ b1,
    const float* __restrict__ W2, const float* __restrict__ b2,
    float* __restrict__ out, int NV) {
  int tid = threadIdx.x;
  int lane = tid & 63, wid = tid >> 6;
  int lo4 = lane & 15, q = lane >> 4;

  BF8 bh[4], bl[4];
#pragma unroll
  for (int ct = 0; ct < 4; ct++) {
    int col = ct * 16 + lo4;
#pragma unroll
    for (int i = 0; i < 8; i++) {
      int k = q * 8 + i;
      int r = (k < 16) ? k : (k + 2);
      float w = W1[r * 64 + col];
      unsigned u = __float_as_uint(w);
      float rem = w - __uint_as_float(u & 0xffff0000u);
      bh[ct].u[i] = (unsigned short)(u >> 16);
      bl[ct].u[i] = (unsigned short)(__float_as_uint(rem) >> 16);
    }
  }
  float b1v[4], w16v[4], w17v[4], w2a[4], w2b[4];
#pragma unroll
  for (int ct = 0; ct < 4; ct++) {
    int j = ct * 16 + lo4;
    b1v[ct] = b1[j];
    w16v[ct] = W1[16 * 64 + j];
    w17v[ct] = W1[17 * 64 + j];
    w2a[ct] = W2[j * 2 + 0];
    w2b[ct] = W2[j * 2 + 1];
  }
  float bias20 = b2[0], bias21 = b2[1];

  int nwaves = gridDim.x * 4;
  int ntiles = (NV + 15) >> 4;
  for (int tb = blockIdx.x * 4 + wid; tb < ntiles; tb += nwaves) {
    int base = tb * 16;
    BF8 ah, al;
    {
      int p = base + lo4;
      float vals[8] = {0.f, 0.f, 0.f, 0.f, 0.f, 0.f, 0.f, 0.f};
      if (p < NV) {
        int node = (int)out[((q < 2) ? 0 : NV) + p];
        const float4* xp = (const float4*)(xh + node * 16 + (q & 1) * 8);
        float4 f0 = xp[0], f1 = xp[1];
        vals[0] = f0.x; vals[1] = f0.y; vals[2] = f0.z; vals[3] = f0.w;
        vals[4] = f1.x; vals[5] = f1.y; vals[6] = f1.z; vals[7] = f1.w;
      }
#pragma unroll
      for (int i = 0; i < 8; i++) {
        unsigned u = __float_as_uint(vals[i]);
        float rem = vals[i] - __uint_as_float(u & 0xffff0000u);
        ah.u[i] = (unsigned short)(u >> 16);
        al.u[i] = (unsigned short)(__float_as_uint(rem) >> 16);
      }
    }
    f32x4 acc[4];
#pragma unroll
    for (int ct = 0; ct < 4; ct++) {
      f32x4 z = {0.f, 0.f, 0.f, 0.f};
      z = __builtin_amdgcn_mfma_f32_16x16x32_bf16(ah.v, bh[ct].v, z, 0, 0, 0);
      z = __builtin_amdgcn_mfma_f32_16x16x32_bf16(ah.v, bl[ct].v, z, 0, 0, 0);
      z = __builtin_amdgcn_mfma_f32_16x16x32_bf16(al.v, bh[ct].v, z, 0, 0, 0);
      acc[ct] = z;
    }
    float o0[4], o1[4];
#pragma unroll
    for (int reg = 0; reg < 4; reg++) {
      int pr = base + q * 4 + reg;
      float2 ea = make_float2(0.f, 0.f);
      if (pr < NV) ea = eat2[pr];
      float s0 = 0.f, s1 = 0.f;
#pragma unroll
      for (int ct = 0; ct < 4; ct++) {
        float h = acc[ct][reg] + b1v[ct] + ea.x * w16v[ct] + ea.y * w17v[ct];
        h = fmaxf(h, 0.f);
        s0 += h * w2a[ct];
        s1 += h * w2b[ct];
      }
      o0[reg] = s0; o1[reg] = s1;
    }
#pragma unroll
    for (int m = 1; m < 16; m <<= 1) {
#pragma unroll
      for (int reg = 0; reg < 4; reg++) {
        o0[reg] += __shfl_xor(o0[reg], m, 64);
        o1[reg] += __shfl_xor(o1[reg], m, 64);
      }
    }
    if (lo4 == 0) {
#pragma unroll
      for (int reg = 0; reg < 4; reg++) {
        int pr = base + q * 4 + reg;
        if (pr < NV) {
          float v0 = bias20 + o0[reg], v1 = bias21 + o1[reg];
          ((float2*)(out + 2 * (size_t)NV))[pr] = make_float2(
              1.f / (1.f + __expf(-v0)), 1.f / (1.f + __expf(-v1)));
        }
      }
    }
  }
}

static inline size_t al64(size_t v) { return (v + 63) & ~(size_t)63; }

extern "C" void kernel_launch(void* const* d_in, const int* in_sizes, int n_in,
                              void* d_out, int out_size, void* d_ws, size_t ws_size,
                              hipStream_t stream) {
  const float* x     = (const float*)d_in[0];
  const int*   edges = (const int*)d_in[1];
  const float* eattr = (const float*)d_in[2];
  const void*  labels= d_in[3];
  const float* Wg    = (const float*)d_in[4];
  const float* atts  = (const float*)d_in[5];
  const float* attd  = (const float*)d_in[6];
  const float* We    = (const float*)d_in[7];
  const float* atte  = (const float*)d_in[8];
  const float* bg    = (const float*)d_in[9];
  const float* W1    = (const float*)d_in[10];
  const float* b1    = (const float*)d_in[11];
  const float* W2    = (const float*)d_in[12];
  const float* b2    = (const float*)d_in[13];
  float* out = (float*)d_out;
  const int NV = out_size / 4;
  const int* src = edges;
  const int* dst = edges + NE;

  char* w = (char*)d_ws;
  float* xh    = (float*)w;   w += al64((size_t)NN * 64);
  uint2* bins  = (uint2*)w;   w += al64((size_t)NE * 8);
  float2* eat2 = (float2*)w;  w += al64((size_t)NV * 8);
  float2* pka  = (float2*)w;  w += al64((size_t)NN * 8);
  float2* pkd  = (float2*)w;  w += al64((size_t)NN * 8);
  int* labN    = (int*)w;     w += al64((size_t)NN * 4);
  int* blkcnt  = (int*)w;     w += al64((size_t)NCB * NBK * 4);
  int* ssum    = (int*)w;     w += al64((size_t)NSTRIP * NBK * 4);
  int* total   = (int*)w;     w += al64((size_t)NBK * 4);
  int* bb      = (int*)w;     w += al64((size_t)(NBK + 1) * 4);
  int* cntc    = (int*)w;     w += al64((size_t)NCB * 4);
  int* offc    = (int*)w;     w += al64((size_t)(NCB + 1) * 4);
  int* cntw    = (int*)w;     w += al64((size_t)NWG * 4);
  int* offw    = (int*)w;     w += al64((size_t)NWG * 4);
  float* c01   = (float*)w;   w += 64;
  int* flags   = (int*)w;     w += 64;

  kdetect<<<1, 256, 0, stream>>>((const unsigned char*)labels, flags);
  klab<<<(NN + 255) / 256, 256, 0, stream>>>(labels, flags, labN);
  kc01<<<1, 64, 0, stream>>>(We, atte, c01);
  knodeA<<<(NN + 255) / 256, 256, 0, stream>>>(x, Wg, atts, attd, labN, pka, pkd);
  khist<<<NCB, THR, 0, stream>>>(src, dst, labN, blkcnt, cntw, cntc);
  kscanc1<<<dim3((NBK + 255) / 256, NSTRIP), 256, 0, stream>>>(blkcnt, ssum);
  kscanc2<<<(NBK + 255) / 256, 256, 0, stream>>>(ssum, total);
  kscan<<<1, 256, 0, stream>>>(total, bb, NBK);
  kaddbb<<<(NBK + 255) / 256, 256, 0, stream>>>(ssum, bb);
  kscan<<<1, 256, 0, stream>>>(cntc, offc, NCB);
  kscanw<<<NCB, 128, 0, stream>>>(cntw, offc, offw);
  kscat<<<NCB, THR, 0, stream>>>(src, dst, eattr, pka, pkd, c01, blkcnt, ssum,
                                 offw, bins, out, eat2, NV);
  kagg<<<NBK, 512, 0, stream>>>(bins, bb, x, Wg, bg, xh);
  if (NV > 0)
    kmlp<<<2048, 256, 0, stream>>>(eat2, xh, W1, b1, W2, b2, out, NV);
}